// Round 5
// baseline (267.578 us; speedup 1.0000x reference)
//
#include <hip/hip_runtime.h>

// ---- problem constants ----
#define BB 2
#define LL 2048
#define DMODEL 1024
#define DSSM 2048
#define NH 32
#define HD 64
#define DST 128
#define CONVD 2304
#define DPROJ 4384
#define CS 64               // SSD chunk size (rechunked; math is exact)
#define NC 32               // LL/CS
#define BLTOT (BB*LL)       // 4096

typedef short v8s __attribute__((ext_vector_type(8)));
typedef float v4f __attribute__((ext_vector_type(4)));

__device__ __forceinline__ float b2f(unsigned short h) {
  union { unsigned int u; float f; } v; v.u = ((unsigned int)h) << 16; return v.f;
}
__device__ __forceinline__ unsigned short f2b(float f) {
  union { float f; unsigned int u; } v; v.f = f;
  unsigned int u = v.u;
  return (unsigned short)((u + 0x7fffu + ((u >> 16) & 1u)) >> 16);
}
__device__ __forceinline__ v4f mfma16(v8s a, v8s b, v4f c) {
  return __builtin_amdgcn_mfma_f32_16x16x32_bf16(a, b, c, 0, 0, 0);
}
// async global->LDS, 16B per lane; LDS dest = wave-uniform base + lane*16
__device__ __forceinline__ void gl_lds16(const unsigned short* g, unsigned short* l) {
  __builtin_amdgcn_global_load_lds(
      (const __attribute__((address_space(1))) void*)(g),
      (__attribute__((address_space(3))) void*)(l), 16, 0, 0);
}

// ---------------- fused fp32 -> bf16 conversion (3 tensors, 1 launch) ----------------
__global__ __launch_bounds__(256) void cvt3_kernel(
    const float* __restrict__ a, unsigned short* __restrict__ oa, int na4,
    const float* __restrict__ b, unsigned short* __restrict__ ob, int nb4,
    const float* __restrict__ c, unsigned short* __restrict__ oc, int nc4)
{
  int i = blockIdx.x * 256 + threadIdx.x;
  const float* src; unsigned short* dst; int j;
  if (i < na4) { src = a; dst = oa; j = i; }
  else if (i < na4 + nb4) { src = b; dst = ob; j = i - na4; }
  else if (i < na4 + nb4 + nc4) { src = c; dst = oc; j = i - na4 - nb4; }
  else return;
  float4 v = ((const float4*)src)[j];
  ushort4 o;
  o.x = f2b(v.x); o.y = f2b(v.y); o.z = f2b(v.z); o.w = f2b(v.w);
  ((ushort4*)dst)[j] = o;
}

// ---------------- bf16 GEMM: 128 x TN tile, 256 threads ----------------
// m97 fragments/swizzle + DOUBLE-BUFFERED LDS with stage-early schedule:
// per K-iter: issue stage(kt+1) -> ds_read+MFMA on buf(kt) -> sched_barrier(0)
// + raw "s_waitcnt vmcnt(0) lgkmcnt(0); s_barrier". The vmcnt wait fires ~1 full
// iteration after the loads were issued (latency hidden) vs m97's zero-age drain;
// barrier count is halved (1/iter). sched_barrier pins MFMAs+ds_reads before the
// barrier (rule #18: "memory" clobber alone doesn't order register-only MFMA);
// lgkmcnt(0) makes cross-wave LDS-read-vs-DMA-write safety airtight (free: LDS
// data was already consumed by the MFMAs). Buffer parity => write-after-read safe.
template<int TN, int OUT_BF16>
__global__ __launch_bounds__(256) void gemm_bt(
    const unsigned short* __restrict__ A, const unsigned short* __restrict__ Bt,
    void* __restrict__ Cout, int M, int N, int K, int ldc)
{
  constexpr int NT = TN / 32;                 // n-tiles per wave
  const int bm = blockIdx.x, bn = blockIdx.y;
  const int tid = threadIdx.x;
  const int wave = tid >> 6, lane = tid & 63;
  const int wm = wave & 1, wn = wave >> 1;
  const int q = lane >> 4, lr = lane & 15;

  __shared__ __align__(16) unsigned short As[2][128 * 64];
  __shared__ __align__(16) unsigned short Bs[2][TN * 64];

  v4f acc[4][NT];
#pragma unroll
  for (int i = 0; i < 4; i++)
#pragma unroll
    for (int j = 0; j < NT; j++) acc[i][j] = v4f{0.f, 0.f, 0.f, 0.f};

  const int lrow = lane >> 3;                 // 0..7 (row within 8-row group)
  const int gchunk = (lane & 7) ^ lrow;       // swizzled source 16B-chunk

#define STAGE_TILE(bufi, k0) do {                                              \
    _Pragma("unroll")                                                          \
    for (int it = 0; it < 4; ++it) {                                           \
      int r = wave * 32 + it * 8 + lrow;                                       \
      gl_lds16(A + (size_t)(bm * 128 + r) * K + (k0) + gchunk * 8,             \
               &As[bufi][(wave * 32 + it * 8) * 64]);                          \
    }                                                                          \
    _Pragma("unroll")                                                          \
    for (int it = 0; it < TN / 32; ++it) {                                     \
      int rloc = wave * (TN / 4) + it * 8;                                     \
      int rb = bn * TN + rloc + lrow; if (rb >= N) rb = N - 1;                 \
      gl_lds16(Bt + (size_t)rb * K + (k0) + gchunk * 8, &Bs[bufi][rloc * 64]); \
    }                                                                          \
  } while (0)

#define WAIT_BARRIER() do {                                                    \
    __builtin_amdgcn_sched_barrier(0);                                         \
    asm volatile("s_waitcnt vmcnt(0) lgkmcnt(0)\ns_barrier" ::: "memory");     \
  } while (0)

  const int nkt = K >> 6;
  STAGE_TILE(0, 0);
  WAIT_BARRIER();

  for (int kt = 0; kt < nkt; ++kt) {
    const int cb = kt & 1;
    if (kt + 1 < nkt) STAGE_TILE(cb ^ 1, (kt + 1) << 6);
    const unsigned short* __restrict__ Ab = As[cb];
    const unsigned short* __restrict__ Bb = Bs[cb];
#pragma unroll
    for (int ks = 0; ks < 64; ks += 32) {
      const int c0 = (ks >> 3) + q;           // 16B-chunk index 0..7
      v8s af[4], bf[NT];
#pragma unroll
      for (int mt = 0; mt < 4; ++mt) {
        int r = wm * 64 + mt * 16 + lr;
        af[mt] = *(const v8s*)&Ab[r * 64 + ((c0 ^ (r & 7)) << 3)];
      }
#pragma unroll
      for (int nt = 0; nt < NT; ++nt) {
        int r = wn * (TN / 2) + nt * 16 + lr;
        bf[nt] = *(const v8s*)&Bb[r * 64 + ((c0 ^ (r & 7)) << 3)];
      }
#pragma unroll
      for (int mt = 0; mt < 4; ++mt)
#pragma unroll
        for (int nt = 0; nt < NT; ++nt)
          acc[mt][nt] = mfma16(af[mt], bf[nt], acc[mt][nt]);
    }
    if (kt + 1 < nkt) WAIT_BARRIER();
  }
#undef STAGE_TILE
#undef WAIT_BARRIER

#pragma unroll
  for (int mt = 0; mt < 4; ++mt) {
#pragma unroll
    for (int nt = 0; nt < NT; ++nt) {
      int row = bm * 128 + wm * 64 + mt * 16 + q * 4;
      int col = bn * TN + wn * (TN / 2) + nt * 16 + lr;
      if (col < N) {
#pragma unroll
        for (int r = 0; r < 4; ++r) {
          float v = acc[mt][nt][r];
          if (OUT_BF16) ((unsigned short*)Cout)[(size_t)(row + r) * ldc + col] = f2b(v);
          else          ((float*)Cout)[(size_t)(row + r) * ldc + col] = v;
        }
      }
    }
  }
}

// ---------------- slim tree conv: B/C cols + dt softplus only ----------------
// (x-portion of the conv is fused into d1_intra's xT staging; x16 buffer eliminated)
__global__ __launch_bounds__(256) void convBC_kernel(
    const unsigned short* __restrict__ C1, const int* __restrict__ cidx,
    const float* __restrict__ convw, const float* __restrict__ convb,
    const float* __restrict__ dtbias,
    unsigned short* __restrict__ Bg16, unsigned short* __restrict__ Cg16,
    float* __restrict__ dtb)
{
  int bl0 = blockIdx.x * 16;           // 16 tokens per block (grid = BLTOT/16 = 256)
  int b = bl0 >> 11;
  int tid = threadIdx.x;
  __shared__ int idxs[64];
  if (tid < 64) {
    int tk = tid >> 2, k = tid & 3;
    idxs[tid] = cidx[b * (4 * LL) + (((bl0 + tk) & 2047) * 4) + k];
  }
  __syncthreads();
  const float4* cw4 = (const float4*)convw;
  int quad = tid & 63;                 // 64 quads cover B/C's 256 cols
  int relc = DSSM + quad * 4;          // xBC-relative col (B/C region)
  float4 w0 = cw4[relc], w1 = cw4[relc + 1], w2 = cw4[relc + 2], w3 = cw4[relc + 3];
  float4 cb = *(const float4*)(convb + relc);
  int tk0 = (tid >> 6) * 4;
#pragma unroll
  for (int tt = 0; tt < 4; ++tt) {
    int tk = tk0 + tt;
    int bl = bl0 + tk;
    ushort4 rv[4];
#pragma unroll
    for (int k = 0; k < 4; ++k) {
      int iv = idxs[tk * 4 + k];
      rv[k] = (iv > 0) ? *(const ushort4*)(C1 + (size_t)(b * LL + iv - 1) * DPROJ + DSSM + relc)
                       : make_ushort4(0, 0, 0, 0);
    }
    float a0 = cb.x + b2f(rv[0].x) * w0.x + b2f(rv[1].x) * w0.y + b2f(rv[2].x) * w0.z + b2f(rv[3].x) * w0.w;
    float a1 = cb.y + b2f(rv[0].y) * w1.x + b2f(rv[1].y) * w1.y + b2f(rv[2].y) * w1.z + b2f(rv[3].y) * w1.w;
    float a2 = cb.z + b2f(rv[0].z) * w2.x + b2f(rv[1].z) * w2.y + b2f(rv[2].z) * w2.z + b2f(rv[3].z) * w2.w;
    float a3 = cb.w + b2f(rv[0].w) * w3.x + b2f(rv[1].w) * w3.y + b2f(rv[2].w) * w3.z + b2f(rv[3].w) * w3.w;
    ushort4 o;
    o.x = f2b(a0 / (1.f + __expf(-a0)));
    o.y = f2b(a1 / (1.f + __expf(-a1)));
    o.z = f2b(a2 / (1.f + __expf(-a2)));
    o.w = f2b(a3 / (1.f + __expf(-a3)));
    int cc = relc - DSSM;
    if (cc < DST) *(ushort4*)(Bg16 + (size_t)bl * DST + cc) = o;
    else          *(ushort4*)(Cg16 + (size_t)bl * DST + (cc - DST)) = o;
  }
  for (int u = tid; u < 16 * NH; u += 256) {   // 16 tokens x 32 heads
    int tk = u >> 5, hh = u & 31;
    int bl = bl0 + tk;
    float raw = b2f(C1[(size_t)bl * DPROJ + DSSM + CONVD + hh]) + dtbias[hh];
    float dtv = (raw > 20.f) ? raw : log1pf(__expf(raw));
    dtb[(size_t)bl * NH + hh] = dtv;
  }
}

// ---------------- SSD intra-chunk: x-conv fused + Yd + D*x, states^T, decays --------
// x tree-conv computed in-kernel directly into xT (bit-identical math to conv_kernel);
// eliminates the x16 HBM round-trip (33.6 MB).
__global__ __launch_bounds__(256) void d1_intra(
    const unsigned short* __restrict__ C1, const int* __restrict__ cidx,
    const float* __restrict__ convw, const float* __restrict__ convb,
    const unsigned short* __restrict__ Bg16,
    const unsigned short* __restrict__ Cg16, const float* __restrict__ dtb,
    const float* __restrict__ A_log, const float* __restrict__ Dp,
    unsigned short* __restrict__ y16, unsigned short* __restrict__ statesb,
    float* __restrict__ cdb, float* __restrict__ acumb)
{
  int gid = blockIdx.x;
  int h = gid & 31, ci = (gid >> 5) & 31, b = gid >> 10;
  int tid = threadIdx.x, wave = tid >> 6, lane = tid & 63, q = lane >> 4, lr = lane & 15;

  __shared__ __align__(16) unsigned short BnG[CS * 136];  // B[s][n]; reused as G[t][s] (stride 72)
  __shared__ __align__(16) unsigned short BTw[DST * 72];  // B^T[n][s] * dec[s] * dt[s]
  __shared__ __align__(16) unsigned short xT[HD * 72];    // x^T[p][s]  (no dt)
  __shared__ float dt_s[CS], ac_s[CS], dec_s[CS];
  __shared__ int idxs[CS * 4];          // tree indices for this chunk's 64 tokens
  __shared__ float wls[HD * 4];         // conv weights for this head's 64 x-cols
  __shared__ float bls[HD];             // conv bias

  const size_t blbase = (size_t)b * LL + ci * CS;
  const size_t chbase = (size_t)(b * NC + ci) * NH + h;
  float Ah = -__expf(A_log[h]);

  // wave0: dt load + shuffle inclusive scan (no barriers)
  if (wave == 0) {
    float d = dtb[(blbase + lane) * NH + h];
    float a = d * Ah;
#pragma unroll
    for (int off = 1; off < 64; off <<= 1) {
      float u = __shfl_up(a, off, 64);
      if (lane >= off) a += u;
    }
    float tot = __shfl(a, 63, 64);
    dt_s[lane] = d;
    ac_s[lane] = a;
    dec_s[lane] = __expf(tot - a);
    acumb[chbase * CS + lane] = a;
    if (lane == 0) cdb[chbase] = __expf(tot);
  }

  // stage B tile (64 x 128)
#pragma unroll
  for (int g = 0; g < 8; ++g) {
    int f = g * 256 + tid;              // s(64) x n-quads(32)
    int s = f >> 5, c4 = (f & 31) * 4;
    *(ushort4*)&BnG[s * 136 + c4] = *(const ushort4*)(Bg16 + (blbase + s) * DST + c4);
  }
  // stage tree indices + conv weights/bias for this head's x-cols
  {
    int s = tid >> 2, k = tid & 3;      // 256 threads = 64 tokens x 4 taps
    idxs[tid] = cidx[b * (4 * LL) + (ci * CS + s) * 4 + k];
  }
  if (tid < HD) *(float4*)&wls[tid * 4] = *(const float4*)(convw + (h * HD + tid) * 4);
  if (tid < HD / 4) *(float4*)&bls[tid * 4] = *(const float4*)(convb + h * HD + tid * 4);
  __syncthreads();                      // barrier 1

  // BTw[n][s] = B[s][n] * dec[s] * dt[s]
#pragma unroll
  for (int g = 0; g < 4; ++g) {
    int f = g * 256 + tid;              // n(128) x sg(8)
    int n = f >> 3, sg = f & 7;
    int s0 = sg * 8;
    ushort4 lo, hi;
    lo.x = f2b(b2f(BnG[(s0 + 0) * 136 + n]) * dec_s[s0 + 0] * dt_s[s0 + 0]);
    lo.y = f2b(b2f(BnG[(s0 + 1) * 136 + n]) * dec_s[s0 + 1] * dt_s[s0 + 1]);
    lo.z = f2b(b2f(BnG[(s0 + 2) * 136 + n]) * dec_s[s0 + 2] * dt_s[s0 + 2]);
    lo.w = f2b(b2f(BnG[(s0 + 3) * 136 + n]) * dec_s[s0 + 3] * dt_s[s0 + 3]);
    hi.x = f2b(b2f(BnG[(s0 + 4) * 136 + n]) * dec_s[s0 + 4] * dt_s[s0 + 4]);
    hi.y = f2b(b2f(BnG[(s0 + 5) * 136 + n]) * dec_s[s0 + 5] * dt_s[s0 + 5]);
    hi.z = f2b(b2f(BnG[(s0 + 6) * 136 + n]) * dec_s[s0 + 6] * dt_s[s0 + 6]);
    hi.w = f2b(b2f(BnG[(s0 + 7) * 136 + n]) * dec_s[s0 + 7] * dt_s[s0 + 7]);
    *(ushort4*)&BTw[n * 72 + s0] = lo;
    *(ushort4*)&BTw[n * 72 + s0 + 4] = hi;
  }

  // S[t][s] = sum_n C[t][n] * B[s][n]  (C A-fragments direct from global)
  v4f accS[4];
#pragma unroll
  for (int i = 0; i < 4; i++) accS[i] = v4f{0.f, 0.f, 0.f, 0.f};
#pragma unroll
  for (int ks = 0; ks < 128; ks += 32) {
    v8s a = *(const v8s*)(Cg16 + (blbase + wave * 16 + lr) * DST + ks + q * 8);
#pragma unroll
    for (int si = 0; si < 4; ++si) {
      v8s bb = *(const v8s*)&BnG[(si * 16 + lr) * 136 + ks + q * 8];
      accS[si] = mfma16(a, bb, accS[si]);
    }
  }

  // fused x tree-conv -> xT[p][s] (writes complete before barrier 2; read after barrier 3)
#pragma unroll
  for (int g = 0; g < 4; ++g) {
    int f = g * 256 + tid;              // s(64) x p-quads(16)
    int s = f >> 4, p4 = (f & 15) * 4;
    ushort4 rv[4];
#pragma unroll
    for (int k = 0; k < 4; ++k) {
      int iv = idxs[s * 4 + k];
      rv[k] = (iv > 0) ? *(const ushort4*)(C1 + (size_t)(b * LL + iv - 1) * DPROJ + DSSM + h * HD + p4)
                       : make_ushort4(0, 0, 0, 0);
    }
    float4 w0 = *(const float4*)&wls[(p4 + 0) * 4];
    float4 w1 = *(const float4*)&wls[(p4 + 1) * 4];
    float4 w2 = *(const float4*)&wls[(p4 + 2) * 4];
    float4 w3 = *(const float4*)&wls[(p4 + 3) * 4];
    float a0 = bls[p4 + 0] + b2f(rv[0].x) * w0.x + b2f(rv[1].x) * w0.y + b2f(rv[2].x) * w0.z + b2f(rv[3].x) * w0.w;
    float a1 = bls[p4 + 1] + b2f(rv[0].y) * w1.x + b2f(rv[1].y) * w1.y + b2f(rv[2].y) * w1.z + b2f(rv[3].y) * w1.w;
    float a2 = bls[p4 + 2] + b2f(rv[0].z) * w2.x + b2f(rv[1].z) * w2.y + b2f(rv[2].z) * w2.z + b2f(rv[3].z) * w2.w;
    float a3 = bls[p4 + 3] + b2f(rv[0].w) * w3.x + b2f(rv[1].w) * w3.y + b2f(rv[2].w) * w3.z + b2f(rv[3].w) * w3.w;
    xT[(p4 + 0) * 72 + s] = f2b(a0 / (1.f + __expf(-a0)));
    xT[(p4 + 1) * 72 + s] = f2b(a1 / (1.f + __expf(-a1)));
    xT[(p4 + 2) * 72 + s] = f2b(a2 / (1.f + __expf(-a2)));
    xT[(p4 + 3) * 72 + s] = f2b(a3 / (1.f + __expf(-a3)));
  }
  __syncthreads();                      // barrier 2 (BnG reads done, xT written)

  // G[t][s] = S * exp(Acum[t]-Acum[s]) * dt[s], masked s<=t; stride 72
  {
    int tbase = wave * 16 + q * 4;
#pragma unroll
    for (int si = 0; si < 4; ++si) {
      int s = si * 16 + lr;
      float ds = dt_s[s], as = ac_s[s];
#pragma unroll
      for (int r = 0; r < 4; ++r) {
        int tt = tbase + r;
        float g = 0.f;
        if (s <= tt) g = accS[si][r] * __expf(ac_s[tt] - as) * ds;
        BnG[tt * 72 + s] = f2b(g);
      }
    }
  }
  __syncthreads();                      // barrier 3

  // Yd[t][p] = G @ x ; states^T[p][n] = sum_s xT[p][s]*BTw[n][s]
  v4f accY[4], accPT[4][2];
#pragma unroll
  for (int i = 0; i < 4; i++) {
    accY[i] = v4f{0.f,0.f,0.f,0.f};
    accPT[i][0] = v4f{0.f,0.f,0.f,0.f};
    accPT[i][1] = v4f{0.f,0.f,0.f,0.f};
  }
  int nw = wave * 32;                   // wave covers n in [nw, nw+32)
#pragma unroll
  for (int ks = 0; ks < 64; ks += 32) {
    v8s xf[4];
#pragma unroll
    for (int i = 0; i < 4; ++i) xf[i] = *(const v8s*)&xT[(i * 16 + lr) * 72 + ks + q * 8];
    v8s aG  = *(const v8s*)&BnG[(wave * 16 + lr) * 72 + ks + q * 8];
    v8s bw0 = *(const v8s*)&BTw[(nw + lr) * 72 + ks + q * 8];
    v8s bw1 = *(const v8s*)&BTw[(nw + 16 + lr) * 72 + ks + q * 8];
#pragma unroll
    for (int nt = 0; nt < 4; ++nt) {
      accY[nt] = mfma16(aG, xf[nt], accY[nt]);
      accPT[nt][0] = mfma16(xf[nt], bw0, accPT[nt][0]);
      accPT[nt][1] = mfma16(xf[nt], bw1, accPT[nt][1]);
    }
  }

  // epilogue: y = Yd + D*x  (x from LDS xT)
  float Dh = Dp[h];
#pragma unroll
  for (int nt = 0; nt < 4; ++nt) {
    int p = nt * 16 + lr;
#pragma unroll
    for (int r = 0; r < 4; ++r) {
      int t = wave * 16 + q * 4 + r;
      float xv = b2f(xT[p * 72 + t]);
      y16[(blbase + t) * DSSM + h * HD + p] = f2b(accY[nt][r] + Dh * xv);
    }
  }
  // epilogue: states^T  (layout [p][n], p<HD rows, n<DST cols)
  size_t sbase = chbase * (DST * HD);
#pragma unroll
  for (int mt = 0; mt < 4; ++mt) {
#pragma unroll
    for (int nt = 0; nt < 2; ++nt) {
      int n = nw + nt * 16 + lr;
#pragma unroll
      for (int r = 0; r < 4; ++r) {
        int p = mt * 16 + q * 4 + r;
        statesb[sbase + (size_t)p * DST + n] = f2b(accPT[mt][nt][r]);
      }
    }
  }
}

// ---------------- state passing: all loads upfront, register scan ----------------
// 2048 blocks: (b,h) x 32 segments of the 8192-elem state; 1 elem/thread over 32 chunks
__global__ __launch_bounds__(256) void d2_scan(
    unsigned short* __restrict__ statesb, const float* __restrict__ cdb)
{
  int g = blockIdx.x;
  int seg = g & 31, bh = g >> 5;
  int b = bh >> 5, h = bh & 31;
  int e = seg * 256 + threadIdx.x;      // 0..8191
  const size_t cstride = (size_t)NH * DST * HD;
  size_t base = ((size_t)(b * NC) * NH + h) * (DST * HD) + e;
  unsigned short st[NC];
#pragma unroll
  for (int ci = 0; ci < NC; ++ci) st[ci] = statesb[base + ci * cstride];
  float run = 0.f;
#pragma unroll
  for (int ci = 0; ci < NC; ++ci) {
    float cd = cdb[(b * NC + ci) * NH + h];
    statesb[base + ci * cstride] = f2b(run);   // prev entering chunk ci
    run = run * cd + b2f(st[ci]);
  }
}

// ---------------- SSD inter-chunk: Y += exp(Acum[t]) * C @ prev^T ----------------
// prev stored [p][n] -> straight vector staging; D*x already folded into d1
__global__ __launch_bounds__(256) void d3_inter(
    const unsigned short* __restrict__ Cg16,
    const unsigned short* __restrict__ statesb, const float* __restrict__ acumb,
    unsigned short* __restrict__ y16)
{
  int gid = blockIdx.x;
  int h = gid & 31, ci = (gid >> 5) & 31, b = gid >> 10;
  int tid = threadIdx.x, wave = tid >> 6, lane = tid & 63, q = lane >> 4, lr = lane & 15;
  __shared__ __align__(16) unsigned short pT[HD * 136];   // prev^T[p][n]
  __shared__ __align__(16) float ys[CS * 68];             // y-stage (fp32)
  __shared__ float ea[CS];
  const size_t blbase = (size_t)b * LL + ci * CS;
  const size_t chbase = (size_t)(b * NC + ci) * NH + h;
  if (tid < CS) ea[tid] = __expf(acumb[chbase * CS + tid]);
  size_t sbase = chbase * (DST * HD);
  // stage prev^T: plain vector copy (64 rows x 128 cols)
#pragma unroll
  for (int g = 0; g < 8; ++g) {
    int f = g * 256 + tid;              // p(64) x n-quads(32)
    int p = f >> 5, c4 = (f & 31) * 4;
    *(ushort4*)&pT[p * 136 + c4] = *(const ushort4*)(statesb + sbase + (size_t)p * DST + c4);
  }
  __syncthreads();
  v4f acc[4];
#pragma unroll
  for (int i = 0; i < 4; i++) acc[i] = v4f{0.f, 0.f, 0.f, 0.f};
#pragma unroll
  for (int ks = 0; ks < 128; ks += 32) {
    v8s a = *(const v8s*)(Cg16 + (blbase + wave * 16 + lr) * DST + ks + q * 8);
#pragma unroll
    for (int nt = 0; nt < 4; ++nt) {
      v8s bb = *(const v8s*)&pT[(nt * 16 + lr) * 136 + ks + q * 8];
      acc[nt] = mfma16(a, bb, acc[nt]);
    }
  }
  // stage Yoff to LDS (fp32), then vectorized RMW epilogue
#pragma unroll
  for (int nt = 0; nt < 4; ++nt) {
#pragma unroll
    for (int r = 0; r < 4; ++r)
      ys[(wave * 16 + q * 4 + r) * 68 + nt * 16 + lr] = acc[nt][r];
  }
  __syncthreads();
#pragma unroll
  for (int it = 0; it < 2; ++it) {
    int unit = it * 256 + tid;          // t(64) x p8(8)
    int t = unit >> 3, p8 = (unit & 7) * 8;
    float ea_t = ea[t];
    size_t off = (blbase + t) * DSSM + h * HD + p8;
    uint4 yv = *(const uint4*)(y16 + off);
    float4 o0 = *(const float4*)&ys[t * 68 + p8];
    float4 o1 = *(const float4*)&ys[t * 68 + p8 + 4];
    const unsigned int* yu = (const unsigned int*)&yv;
    float oo[8] = {o0.x, o0.y, o0.z, o0.w, o1.x, o1.y, o1.z, o1.w};
    unsigned int ro[4];
#pragma unroll
    for (int d = 0; d < 4; ++d) {
      unsigned short y0 = (unsigned short)(yu[d] & 0xffffu), y1 = (unsigned short)(yu[d] >> 16);
      float v0 = b2f(y0) + ea_t * oo[d * 2 + 0];
      float v1 = b2f(y1) + ea_t * oo[d * 2 + 1];
      ro[d] = (unsigned int)f2b(v0) | ((unsigned int)f2b(v1) << 16);
    }
    *(uint4*)(y16 + off) = make_uint4(ro[0], ro[1], ro[2], ro[3]);
  }
}

// ---------------- gated RMSNorm (vectorized) ----------------
__global__ __launch_bounds__(256) void norm_kernel(
    const unsigned short* __restrict__ y16, const unsigned short* __restrict__ C1,
    const float* __restrict__ normw, unsigned short* __restrict__ yzn)
{
  int bl = blockIdx.x;
  int tid = threadIdx.x;
  int wave = tid >> 6, lane = tid & 63;
  int c8 = tid * 8;
  uint4 yv = *(const uint4*)(y16 + (size_t)bl * DSSM + c8);
  uint4 zv = *(const uint4*)(C1 + (size_t)bl * DPROJ + c8);   // z = first 2048 cols
  const unsigned int* yu = (const unsigned int*)&yv;
  const unsigned int* zu = (const unsigned int*)&zv;
  float vals[8];
  float ss = 0.f;
#pragma unroll
  for (int d = 0; d < 4; ++d) {
    unsigned short y0 = (unsigned short)(yu[d] & 0xffffu), y1 = (unsigned short)(yu[d] >> 16);
    unsigned short z0 = (unsigned short)(zu[d] & 0xffffu), z1 = (unsigned short)(zu[d] >> 16);
    float zf0 = b2f(z0), zf1 = b2f(z1);
    float v0 = b2f(y0) * (zf0 / (1.f + __expf(-zf0)));
    float v1 = b2f(y1) * (zf1 / (1.f + __expf(-zf1)));
    vals[d * 2] = v0; vals[d * 2 + 1] = v1;
    ss += v0 * v0 + v1 * v1;
  }
#pragma unroll
  for (int off = 32; off > 0; off >>= 1) ss += __shfl_down(ss, off);
  __shared__ float red[4];
  if (lane == 0) red[wave] = ss;
  __syncthreads();
  float tot = red[0] + red[1] + red[2] + red[3];
  float scale = rsqrtf(tot * (1.f / 2048.f) + 1e-5f);
  float4 w0 = *(const float4*)(normw + c8);
  float4 w1 = *(const float4*)(normw + c8 + 4);
  float ws[8] = {w0.x, w0.y, w0.z, w0.w, w1.x, w1.y, w1.z, w1.w};
  unsigned int ro[4];
#pragma unroll
  for (int d = 0; d < 4; ++d) {
    unsigned short r0 = f2b(vals[d * 2] * scale * ws[d * 2]);
    unsigned short r1 = f2b(vals[d * 2 + 1] * scale * ws[d * 2 + 1]);
    ro[d] = (unsigned int)r0 | ((unsigned int)r1 << 16);
  }
  *(uint4*)(yzn + (size_t)bl * DSSM + c8) = make_uint4(ro[0], ro[1], ro[2], ro[3]);
}

// ---------------- host launch ----------------
extern "C" void kernel_launch(void* const* d_in, const int* in_sizes, int n_in,
                              void* d_out, int out_size, void* d_ws, size_t ws_size,
                              hipStream_t stream) {
  const float* u      = (const float*)d_in[0];
  const int*   cidx   = (const int*)d_in[1];
  const float* W_in   = (const float*)d_in[2];
  const float* convw  = (const float*)d_in[3];
  const float* convb  = (const float*)d_in[4];
  const float* dtbias = (const float*)d_in[5];
  const float* A_log  = (const float*)d_in[6];
  const float* Dp     = (const float*)d_in[7];
  const float* normw  = (const float*)d_in[8];
  const float* W_out  = (const float*)d_in[9];

  char* w = (char*)d_ws;
  size_t off = 0;
  auto alloc = [&](size_t bytes) { char* p = w + off; off += (bytes + 255) & ~(size_t)255; return p; };
  unsigned short* u16     = (unsigned short*)alloc((size_t)BLTOT * DMODEL * 2);
  unsigned short* Win16   = (unsigned short*)alloc((size_t)DPROJ * DMODEL * 2);
  unsigned short* Wout16  = (unsigned short*)alloc((size_t)DMODEL * DSSM * 2);
  unsigned short* C1      = (unsigned short*)alloc((size_t)BLTOT * DPROJ * 2);
  unsigned short* Bg16    = (unsigned short*)alloc((size_t)BLTOT * DST * 2);
  unsigned short* Cg16    = (unsigned short*)alloc((size_t)BLTOT * DST * 2);
  float*          dtb     = (float*)alloc((size_t)BLTOT * NH * 4);
  float*          acumb   = (float*)alloc((size_t)BB * NC * NH * CS * 4);
  unsigned short* y16     = (unsigned short*)alloc((size_t)BLTOT * DSSM * 2);
  unsigned short* statesb = (unsigned short*)alloc((size_t)BB * NC * NH * DST * HD * 2);
  float*          cdb     = (float*)alloc((size_t)BB * NC * NH * 4);
  unsigned short* yzn     = (unsigned short*)alloc((size_t)BLTOT * DSSM * 2);

  const int na4 = BLTOT * DMODEL / 4, nb4 = DPROJ * DMODEL / 4, nc4 = DMODEL * DSSM / 4;
  cvt3_kernel<<<(na4 + nb4 + nc4 + 255) / 256, 256, 0, stream>>>(
      u, u16, na4, W_in, Win16, nb4, W_out, Wout16, nc4);

  // zxbcdt = u @ W_in^T   (bf16 out, ld 4384) — 128x128 tiles, double-buffered pipeline
  gemm_bt<128, 1><<<dim3(BLTOT / 128, (DPROJ + 127) / 128), 256, 0, stream>>>(
      u16, Win16, C1, BLTOT, DPROJ, DMODEL, DPROJ);
  convBC_kernel<<<BLTOT / 16, 256, 0, stream>>>(C1, cidx, convw, convb, dtbias, Bg16, Cg16, dtb);
  d1_intra<<<BB * NC * NH, 256, 0, stream>>>(C1, cidx, convw, convb, Bg16, Cg16, dtb,
                                             A_log, Dp, y16, statesb, cdb, acumb);
  d2_scan<<<BB * NH * 32, 256, 0, stream>>>(statesb, cdb);
  d3_inter<<<BB * NC * NH, 256, 0, stream>>>(Cg16, statesb, acumb, y16);
  norm_kernel<<<BLTOT, 256, 0, stream>>>(y16, C1, normw, yzn);
  // out = yzn @ W_out^T   (fp32 out) — 128x64 tiles, double-buffered pipeline
  gemm_bt<64, 0><<<dim3(BLTOT / 128, DMODEL / 64), 256, 0, stream>>>(
      yzn, Wout16, (float*)d_out, BLTOT, DMODEL, DSSM, DMODEL);
}

// Round 6
// 256.365 us; speedup vs baseline: 1.0437x; 1.0437x over previous
//
#include <hip/hip_runtime.h>

// ---- problem constants ----
#define BB 2
#define LL 2048
#define DMODEL 1024
#define DSSM 2048
#define NH 32
#define HD 64
#define DST 128
#define CONVD 2304
#define DPROJ 4384
#define CS 64               // SSD chunk size (rechunked; math is exact)
#define NC 32               // LL/CS
#define BLTOT (BB*LL)       // 4096

typedef short v8s __attribute__((ext_vector_type(8)));
typedef float v4f __attribute__((ext_vector_type(4)));

__device__ __forceinline__ float b2f(unsigned short h) {
  union { unsigned int u; float f; } v; v.u = ((unsigned int)h) << 16; return v.f;
}
__device__ __forceinline__ unsigned short f2b(float f) {
  union { float f; unsigned int u; } v; v.f = f;
  unsigned int u = v.u;
  return (unsigned short)((u + 0x7fffu + ((u >> 16) & 1u)) >> 16);
}
__device__ __forceinline__ v4f mfma16(v8s a, v8s b, v4f c) {
  return __builtin_amdgcn_mfma_f32_16x16x32_bf16(a, b, c, 0, 0, 0);
}
// async global->LDS, 16B per lane; LDS dest = wave-uniform base + lane*16
__device__ __forceinline__ void gl_lds16(const unsigned short* g, unsigned short* l) {
  __builtin_amdgcn_global_load_lds(
      (const __attribute__((address_space(1))) void*)(g),
      (__attribute__((address_space(3))) void*)(l), 16, 0, 0);
}

// ---------------- fused fp32 -> bf16 conversion (3 tensors, 1 launch) ----------------
__global__ __launch_bounds__(256) void cvt3_kernel(
    const float* __restrict__ a, unsigned short* __restrict__ oa, int na4,
    const float* __restrict__ b, unsigned short* __restrict__ ob, int nb4,
    const float* __restrict__ c, unsigned short* __restrict__ oc, int nc4)
{
  int i = blockIdx.x * 256 + threadIdx.x;
  const float* src; unsigned short* dst; int j;
  if (i < na4) { src = a; dst = oa; j = i; }
  else if (i < na4 + nb4) { src = b; dst = ob; j = i - na4; }
  else if (i < na4 + nb4 + nc4) { src = c; dst = oc; j = i - na4 - nb4; }
  else return;
  float4 v = ((const float4*)src)[j];
  ushort4 o;
  o.x = f2b(v.x); o.y = f2b(v.y); o.z = f2b(v.z); o.w = f2b(v.w);
  ((ushort4*)dst)[j] = o;
}

// ---------------- bf16 GEMM: 128 x TN tile, 256 threads ----------------
// DBUF=0: exact r0 single-buffer m97 loop — best for gemm1 (TN=128): 32 KB LDS keeps
//   4+ blocks/CU; cross-block wave overlap hides the pre-barrier drain (measured:
//   every pipelining variant at TN=128 was neutral/negative because LDS growth cut
//   occupancy — r1 8-phase 64->55% slower, r5 dbuf 55->63 µs).
// DBUF=1: stage-early double-buffer — best for gemm2 (TN=64): grid is 2 blocks/CU
//   (512 blocks) and dbuf LDS (48 KB) still allows 3/CU, so the pipeline is free
//   (r5 A/B: gemm2 improved ~3.6 µs under dbuf while gemm1 regressed).
template<int TN, int OUT_BF16, int DBUF>
__global__ __launch_bounds__(256) void gemm_bt(
    const unsigned short* __restrict__ A, const unsigned short* __restrict__ Bt,
    void* __restrict__ Cout, int M, int N, int K, int ldc)
{
  constexpr int NT = TN / 32;                 // n-tiles per wave
  constexpr int NB = DBUF ? 2 : 1;
  const int bm = blockIdx.x, bn = blockIdx.y;
  const int tid = threadIdx.x;
  const int wave = tid >> 6, lane = tid & 63;
  const int wm = wave & 1, wn = wave >> 1;
  const int q = lane >> 4, lr = lane & 15;

  __shared__ __align__(16) unsigned short As[NB][128 * 64];
  __shared__ __align__(16) unsigned short Bs[NB][TN * 64];

  v4f acc[4][NT];
#pragma unroll
  for (int i = 0; i < 4; i++)
#pragma unroll
    for (int j = 0; j < NT; j++) acc[i][j] = v4f{0.f, 0.f, 0.f, 0.f};

  const int lrow = lane >> 3;                 // 0..7 (row within 8-row group)
  const int gchunk = (lane & 7) ^ lrow;       // swizzled source 16B-chunk

#define STAGE_TILE(bufi, k0) do {                                              \
    _Pragma("unroll")                                                          \
    for (int it = 0; it < 4; ++it) {                                           \
      int r = wave * 32 + it * 8 + lrow;                                       \
      gl_lds16(A + (size_t)(bm * 128 + r) * K + (k0) + gchunk * 8,             \
               &As[bufi][(wave * 32 + it * 8) * 64]);                          \
    }                                                                          \
    _Pragma("unroll")                                                          \
    for (int it = 0; it < TN / 32; ++it) {                                     \
      int rloc = wave * (TN / 4) + it * 8;                                     \
      int rb = bn * TN + rloc + lrow; if (rb >= N) rb = N - 1;                 \
      gl_lds16(Bt + (size_t)rb * K + (k0) + gchunk * 8, &Bs[bufi][rloc * 64]); \
    }                                                                          \
  } while (0)

#define COMPUTE_TILE(bufi) do {                                                \
    const unsigned short* __restrict__ Ab = As[bufi];                          \
    const unsigned short* __restrict__ Bb = Bs[bufi];                          \
    _Pragma("unroll")                                                          \
    for (int ks = 0; ks < 64; ks += 32) {                                      \
      const int c0 = (ks >> 3) + q;                                            \
      v8s af[4], bf[NT];                                                       \
      _Pragma("unroll")                                                        \
      for (int mt = 0; mt < 4; ++mt) {                                         \
        int r = wm * 64 + mt * 16 + lr;                                        \
        af[mt] = *(const v8s*)&Ab[r * 64 + ((c0 ^ (r & 7)) << 3)];             \
      }                                                                        \
      _Pragma("unroll")                                                        \
      for (int nt = 0; nt < NT; ++nt) {                                        \
        int r = wn * (TN / 2) + nt * 16 + lr;                                  \
        bf[nt] = *(const v8s*)&Bb[r * 64 + ((c0 ^ (r & 7)) << 3)];             \
      }                                                                        \
      _Pragma("unroll")                                                        \
      for (int mt = 0; mt < 4; ++mt)                                           \
        _Pragma("unroll")                                                      \
        for (int nt = 0; nt < NT; ++nt)                                        \
          acc[mt][nt] = mfma16(af[mt], bf[nt], acc[mt][nt]);                   \
    }                                                                          \
  } while (0)

#define WAIT_BARRIER() do {                                                    \
    __builtin_amdgcn_sched_barrier(0);                                         \
    asm volatile("s_waitcnt vmcnt(0) lgkmcnt(0)\ns_barrier" ::: "memory");     \
  } while (0)

  if constexpr (DBUF == 0) {
    // r0-exact single-buffer loop
    for (int k0 = 0; k0 < K; k0 += 64) {
      __syncthreads();
      STAGE_TILE(0, k0);
      __syncthreads();
      COMPUTE_TILE(0);
    }
  } else {
    const int nkt = K >> 6;
    STAGE_TILE(0, 0);
    WAIT_BARRIER();
    for (int kt = 0; kt < nkt; ++kt) {
      const int cb = kt & 1;
      if (kt + 1 < nkt) STAGE_TILE(cb ^ 1, (kt + 1) << 6);
      COMPUTE_TILE(cb);
      if (kt + 1 < nkt) WAIT_BARRIER();
    }
  }
#undef STAGE_TILE
#undef COMPUTE_TILE
#undef WAIT_BARRIER

#pragma unroll
  for (int mt = 0; mt < 4; ++mt) {
#pragma unroll
    for (int nt = 0; nt < NT; ++nt) {
      int row = bm * 128 + wm * 64 + mt * 16 + q * 4;
      int col = bn * TN + wn * (TN / 2) + nt * 16 + lr;
      if (col < N) {
#pragma unroll
        for (int r = 0; r < 4; ++r) {
          float v = acc[mt][nt][r];
          if (OUT_BF16) ((unsigned short*)Cout)[(size_t)(row + r) * ldc + col] = f2b(v);
          else          ((float*)Cout)[(size_t)(row + r) * ldc + col] = v;
        }
      }
    }
  }
}

// ---------------- slim tree conv: B/C cols + dt softplus only ----------------
// (x-portion of the conv is fused into d1_intra's xT staging; x16 buffer eliminated)
__global__ __launch_bounds__(256) void convBC_kernel(
    const unsigned short* __restrict__ C1, const int* __restrict__ cidx,
    const float* __restrict__ convw, const float* __restrict__ convb,
    const float* __restrict__ dtbias,
    unsigned short* __restrict__ Bg16, unsigned short* __restrict__ Cg16,
    float* __restrict__ dtb)
{
  int bl0 = blockIdx.x * 16;           // 16 tokens per block (grid = BLTOT/16 = 256)
  int b = bl0 >> 11;
  int tid = threadIdx.x;
  __shared__ int idxs[64];
  if (tid < 64) {
    int tk = tid >> 2, k = tid & 3;
    idxs[tid] = cidx[b * (4 * LL) + (((bl0 + tk) & 2047) * 4) + k];
  }
  __syncthreads();
  const float4* cw4 = (const float4*)convw;
  int quad = tid & 63;                 // 64 quads cover B/C's 256 cols
  int relc = DSSM + quad * 4;          // xBC-relative col (B/C region)
  float4 w0 = cw4[relc], w1 = cw4[relc + 1], w2 = cw4[relc + 2], w3 = cw4[relc + 3];
  float4 cb = *(const float4*)(convb + relc);
  int tk0 = (tid >> 6) * 4;
#pragma unroll
  for (int tt = 0; tt < 4; ++tt) {
    int tk = tk0 + tt;
    int bl = bl0 + tk;
    ushort4 rv[4];
#pragma unroll
    for (int k = 0; k < 4; ++k) {
      int iv = idxs[tk * 4 + k];
      rv[k] = (iv > 0) ? *(const ushort4*)(C1 + (size_t)(b * LL + iv - 1) * DPROJ + DSSM + relc)
                       : make_ushort4(0, 0, 0, 0);
    }
    float a0 = cb.x + b2f(rv[0].x) * w0.x + b2f(rv[1].x) * w0.y + b2f(rv[2].x) * w0.z + b2f(rv[3].x) * w0.w;
    float a1 = cb.y + b2f(rv[0].y) * w1.x + b2f(rv[1].y) * w1.y + b2f(rv[2].y) * w1.z + b2f(rv[3].y) * w1.w;
    float a2 = cb.z + b2f(rv[0].z) * w2.x + b2f(rv[1].z) * w2.y + b2f(rv[2].z) * w2.z + b2f(rv[3].z) * w2.w;
    float a3 = cb.w + b2f(rv[0].w) * w3.x + b2f(rv[1].w) * w3.y + b2f(rv[2].w) * w3.z + b2f(rv[3].w) * w3.w;
    ushort4 o;
    o.x = f2b(a0 / (1.f + __expf(-a0)));
    o.y = f2b(a1 / (1.f + __expf(-a1)));
    o.z = f2b(a2 / (1.f + __expf(-a2)));
    o.w = f2b(a3 / (1.f + __expf(-a3)));
    int cc = relc - DSSM;
    if (cc < DST) *(ushort4*)(Bg16 + (size_t)bl * DST + cc) = o;
    else          *(ushort4*)(Cg16 + (size_t)bl * DST + (cc - DST)) = o;
  }
  for (int u = tid; u < 16 * NH; u += 256) {   // 16 tokens x 32 heads
    int tk = u >> 5, hh = u & 31;
    int bl = bl0 + tk;
    float raw = b2f(C1[(size_t)bl * DPROJ + DSSM + CONVD + hh]) + dtbias[hh];
    float dtv = (raw > 20.f) ? raw : log1pf(__expf(raw));
    dtb[(size_t)bl * NH + hh] = dtv;
  }
}

// ---------------- SSD intra-chunk: x-conv fused + Yd + D*x, states^T, decays --------
// x tree-conv computed in-kernel directly into xT (bit-identical math to conv_kernel);
// eliminates the x16 HBM round-trip (33.6 MB).
__global__ __launch_bounds__(256) void d1_intra(
    const unsigned short* __restrict__ C1, const int* __restrict__ cidx,
    const float* __restrict__ convw, const float* __restrict__ convb,
    const unsigned short* __restrict__ Bg16,
    const unsigned short* __restrict__ Cg16, const float* __restrict__ dtb,
    const float* __restrict__ A_log, const float* __restrict__ Dp,
    unsigned short* __restrict__ y16, unsigned short* __restrict__ statesb,
    float* __restrict__ cdb, float* __restrict__ acumb)
{
  int gid = blockIdx.x;
  int h = gid & 31, ci = (gid >> 5) & 31, b = gid >> 10;
  int tid = threadIdx.x, wave = tid >> 6, lane = tid & 63, q = lane >> 4, lr = lane & 15;

  __shared__ __align__(16) unsigned short BnG[CS * 136];  // B[s][n]; reused as G[t][s] (stride 72)
  __shared__ __align__(16) unsigned short BTw[DST * 72];  // B^T[n][s] * dec[s] * dt[s]
  __shared__ __align__(16) unsigned short xT[HD * 72];    // x^T[p][s]  (no dt)
  __shared__ float dt_s[CS], ac_s[CS], dec_s[CS];
  __shared__ int idxs[CS * 4];          // tree indices for this chunk's 64 tokens
  __shared__ float wls[HD * 4];         // conv weights for this head's 64 x-cols
  __shared__ float bls[HD];             // conv bias

  const size_t blbase = (size_t)b * LL + ci * CS;
  const size_t chbase = (size_t)(b * NC + ci) * NH + h;
  float Ah = -__expf(A_log[h]);

  // wave0: dt load + shuffle inclusive scan (no barriers)
  if (wave == 0) {
    float d = dtb[(blbase + lane) * NH + h];
    float a = d * Ah;
#pragma unroll
    for (int off = 1; off < 64; off <<= 1) {
      float u = __shfl_up(a, off, 64);
      if (lane >= off) a += u;
    }
    float tot = __shfl(a, 63, 64);
    dt_s[lane] = d;
    ac_s[lane] = a;
    dec_s[lane] = __expf(tot - a);
    acumb[chbase * CS + lane] = a;
    if (lane == 0) cdb[chbase] = __expf(tot);
  }

  // stage B tile (64 x 128)
#pragma unroll
  for (int g = 0; g < 8; ++g) {
    int f = g * 256 + tid;              // s(64) x n-quads(32)
    int s = f >> 5, c4 = (f & 31) * 4;
    *(ushort4*)&BnG[s * 136 + c4] = *(const ushort4*)(Bg16 + (blbase + s) * DST + c4);
  }
  // stage tree indices + conv weights/bias for this head's x-cols
  {
    int s = tid >> 2, k = tid & 3;      // 256 threads = 64 tokens x 4 taps
    idxs[tid] = cidx[b * (4 * LL) + (ci * CS + s) * 4 + k];
  }
  if (tid < HD) *(float4*)&wls[tid * 4] = *(const float4*)(convw + (h * HD + tid) * 4);
  if (tid < HD / 4) *(float4*)&bls[tid * 4] = *(const float4*)(convb + h * HD + tid * 4);
  __syncthreads();                      // barrier 1

  // BTw[n][s] = B[s][n] * dec[s] * dt[s]
#pragma unroll
  for (int g = 0; g < 4; ++g) {
    int f = g * 256 + tid;              // n(128) x sg(8)
    int n = f >> 3, sg = f & 7;
    int s0 = sg * 8;
    ushort4 lo, hi;
    lo.x = f2b(b2f(BnG[(s0 + 0) * 136 + n]) * dec_s[s0 + 0] * dt_s[s0 + 0]);
    lo.y = f2b(b2f(BnG[(s0 + 1) * 136 + n]) * dec_s[s0 + 1] * dt_s[s0 + 1]);
    lo.z = f2b(b2f(BnG[(s0 + 2) * 136 + n]) * dec_s[s0 + 2] * dt_s[s0 + 2]);
    lo.w = f2b(b2f(BnG[(s0 + 3) * 136 + n]) * dec_s[s0 + 3] * dt_s[s0 + 3]);
    hi.x = f2b(b2f(BnG[(s0 + 4) * 136 + n]) * dec_s[s0 + 4] * dt_s[s0 + 4]);
    hi.y = f2b(b2f(BnG[(s0 + 5) * 136 + n]) * dec_s[s0 + 5] * dt_s[s0 + 5]);
    hi.z = f2b(b2f(BnG[(s0 + 6) * 136 + n]) * dec_s[s0 + 6] * dt_s[s0 + 6]);
    hi.w = f2b(b2f(BnG[(s0 + 7) * 136 + n]) * dec_s[s0 + 7] * dt_s[s0 + 7]);
    *(ushort4*)&BTw[n * 72 + s0] = lo;
    *(ushort4*)&BTw[n * 72 + s0 + 4] = hi;
  }

  // S[t][s] = sum_n C[t][n] * B[s][n]  (C A-fragments direct from global)
  v4f accS[4];
#pragma unroll
  for (int i = 0; i < 4; i++) accS[i] = v4f{0.f, 0.f, 0.f, 0.f};
#pragma unroll
  for (int ks = 0; ks < 128; ks += 32) {
    v8s a = *(const v8s*)(Cg16 + (blbase + wave * 16 + lr) * DST + ks + q * 8);
#pragma unroll
    for (int si = 0; si < 4; ++si) {
      v8s bb = *(const v8s*)&BnG[(si * 16 + lr) * 136 + ks + q * 8];
      accS[si] = mfma16(a, bb, accS[si]);
    }
  }

  // fused x tree-conv -> xT[p][s] (writes complete before barrier 2; read after barrier 3)
#pragma unroll
  for (int g = 0; g < 4; ++g) {
    int f = g * 256 + tid;              // s(64) x p-quads(16)
    int s = f >> 4, p4 = (f & 15) * 4;
    ushort4 rv[4];
#pragma unroll
    for (int k = 0; k < 4; ++k) {
      int iv = idxs[s * 4 + k];
      rv[k] = (iv > 0) ? *(const ushort4*)(C1 + (size_t)(b * LL + iv - 1) * DPROJ + DSSM + h * HD + p4)
                       : make_ushort4(0, 0, 0, 0);
    }
    float4 w0 = *(const float4*)&wls[(p4 + 0) * 4];
    float4 w1 = *(const float4*)&wls[(p4 + 1) * 4];
    float4 w2 = *(const float4*)&wls[(p4 + 2) * 4];
    float4 w3 = *(const float4*)&wls[(p4 + 3) * 4];
    float a0 = bls[p4 + 0] + b2f(rv[0].x) * w0.x + b2f(rv[1].x) * w0.y + b2f(rv[2].x) * w0.z + b2f(rv[3].x) * w0.w;
    float a1 = bls[p4 + 1] + b2f(rv[0].y) * w1.x + b2f(rv[1].y) * w1.y + b2f(rv[2].y) * w1.z + b2f(rv[3].y) * w1.w;
    float a2 = bls[p4 + 2] + b2f(rv[0].z) * w2.x + b2f(rv[1].z) * w2.y + b2f(rv[2].z) * w2.z + b2f(rv[3].z) * w2.w;
    float a3 = bls[p4 + 3] + b2f(rv[0].w) * w3.x + b2f(rv[1].w) * w3.y + b2f(rv[2].w) * w3.z + b2f(rv[3].w) * w3.w;
    xT[(p4 + 0) * 72 + s] = f2b(a0 / (1.f + __expf(-a0)));
    xT[(p4 + 1) * 72 + s] = f2b(a1 / (1.f + __expf(-a1)));
    xT[(p4 + 2) * 72 + s] = f2b(a2 / (1.f + __expf(-a2)));
    xT[(p4 + 3) * 72 + s] = f2b(a3 / (1.f + __expf(-a3)));
  }
  __syncthreads();                      // barrier 2 (BnG reads done, xT written)

  // G[t][s] = S * exp(Acum[t]-Acum[s]) * dt[s], masked s<=t; stride 72
  {
    int tbase = wave * 16 + q * 4;
#pragma unroll
    for (int si = 0; si < 4; ++si) {
      int s = si * 16 + lr;
      float ds = dt_s[s], as = ac_s[s];
#pragma unroll
      for (int r = 0; r < 4; ++r) {
        int tt = tbase + r;
        float g = 0.f;
        if (s <= tt) g = accS[si][r] * __expf(ac_s[tt] - as) * ds;
        BnG[tt * 72 + s] = f2b(g);
      }
    }
  }
  __syncthreads();                      // barrier 3

  // Yd[t][p] = G @ x ; states^T[p][n] = sum_s xT[p][s]*BTw[n][s]
  v4f accY[4], accPT[4][2];
#pragma unroll
  for (int i = 0; i < 4; i++) {
    accY[i] = v4f{0.f,0.f,0.f,0.f};
    accPT[i][0] = v4f{0.f,0.f,0.f,0.f};
    accPT[i][1] = v4f{0.f,0.f,0.f,0.f};
  }
  int nw = wave * 32;                   // wave covers n in [nw, nw+32)
#pragma unroll
  for (int ks = 0; ks < 64; ks += 32) {
    v8s xf[4];
#pragma unroll
    for (int i = 0; i < 4; ++i) xf[i] = *(const v8s*)&xT[(i * 16 + lr) * 72 + ks + q * 8];
    v8s aG  = *(const v8s*)&BnG[(wave * 16 + lr) * 72 + ks + q * 8];
    v8s bw0 = *(const v8s*)&BTw[(nw + lr) * 72 + ks + q * 8];
    v8s bw1 = *(const v8s*)&BTw[(nw + 16 + lr) * 72 + ks + q * 8];
#pragma unroll
    for (int nt = 0; nt < 4; ++nt) {
      accY[nt] = mfma16(aG, xf[nt], accY[nt]);
      accPT[nt][0] = mfma16(xf[nt], bw0, accPT[nt][0]);
      accPT[nt][1] = mfma16(xf[nt], bw1, accPT[nt][1]);
    }
  }

  // epilogue: y = Yd + D*x  (x from LDS xT)
  float Dh = Dp[h];
#pragma unroll
  for (int nt = 0; nt < 4; ++nt) {
    int p = nt * 16 + lr;
#pragma unroll
    for (int r = 0; r < 4; ++r) {
      int t = wave * 16 + q * 4 + r;
      float xv = b2f(xT[p * 72 + t]);
      y16[(blbase + t) * DSSM + h * HD + p] = f2b(accY[nt][r] + Dh * xv);
    }
  }
  // epilogue: states^T  (layout [p][n], p<HD rows, n<DST cols)
  size_t sbase = chbase * (DST * HD);
#pragma unroll
  for (int mt = 0; mt < 4; ++mt) {
#pragma unroll
    for (int nt = 0; nt < 2; ++nt) {
      int n = nw + nt * 16 + lr;
#pragma unroll
      for (int r = 0; r < 4; ++r) {
        int p = mt * 16 + q * 4 + r;
        statesb[sbase + (size_t)p * DST + n] = f2b(accPT[mt][nt][r]);
      }
    }
  }
}

// ---------------- state passing: all loads upfront, register scan ----------------
// 2048 blocks: (b,h) x 32 segments of the 8192-elem state; 1 elem/thread over 32 chunks
__global__ __launch_bounds__(256) void d2_scan(
    unsigned short* __restrict__ statesb, const float* __restrict__ cdb)
{
  int g = blockIdx.x;
  int seg = g & 31, bh = g >> 5;
  int b = bh >> 5, h = bh & 31;
  int e = seg * 256 + threadIdx.x;      // 0..8191
  const size_t cstride = (size_t)NH * DST * HD;
  size_t base = ((size_t)(b * NC) * NH + h) * (DST * HD) + e;
  unsigned short st[NC];
#pragma unroll
  for (int ci = 0; ci < NC; ++ci) st[ci] = statesb[base + ci * cstride];
  float run = 0.f;
#pragma unroll
  for (int ci = 0; ci < NC; ++ci) {
    float cd = cdb[(b * NC + ci) * NH + h];
    statesb[base + ci * cstride] = f2b(run);   // prev entering chunk ci
    run = run * cd + b2f(st[ci]);
  }
}

// ---------------- SSD inter-chunk: Y += exp(Acum[t]) * C @ prev^T ----------------
// prev stored [p][n] -> straight vector staging; D*x already folded into d1
__global__ __launch_bounds__(256) void d3_inter(
    const unsigned short* __restrict__ Cg16,
    const unsigned short* __restrict__ statesb, const float* __restrict__ acumb,
    unsigned short* __restrict__ y16)
{
  int gid = blockIdx.x;
  int h = gid & 31, ci = (gid >> 5) & 31, b = gid >> 10;
  int tid = threadIdx.x, wave = tid >> 6, lane = tid & 63, q = lane >> 4, lr = lane & 15;
  __shared__ __align__(16) unsigned short pT[HD * 136];   // prev^T[p][n]
  __shared__ __align__(16) float ys[CS * 68];             // y-stage (fp32)
  __shared__ float ea[CS];
  const size_t blbase = (size_t)b * LL + ci * CS;
  const size_t chbase = (size_t)(b * NC + ci) * NH + h;
  if (tid < CS) ea[tid] = __expf(acumb[chbase * CS + tid]);
  size_t sbase = chbase * (DST * HD);
  // stage prev^T: plain vector copy (64 rows x 128 cols)
#pragma unroll
  for (int g = 0; g < 8; ++g) {
    int f = g * 256 + tid;              // p(64) x n-quads(32)
    int p = f >> 5, c4 = (f & 31) * 4;
    *(ushort4*)&pT[p * 136 + c4] = *(const ushort4*)(statesb + sbase + (size_t)p * DST + c4);
  }
  __syncthreads();
  v4f acc[4];
#pragma unroll
  for (int i = 0; i < 4; i++) acc[i] = v4f{0.f, 0.f, 0.f, 0.f};
#pragma unroll
  for (int ks = 0; ks < 128; ks += 32) {
    v8s a = *(const v8s*)(Cg16 + (blbase + wave * 16 + lr) * DST + ks + q * 8);
#pragma unroll
    for (int nt = 0; nt < 4; ++nt) {
      v8s bb = *(const v8s*)&pT[(nt * 16 + lr) * 136 + ks + q * 8];
      acc[nt] = mfma16(a, bb, acc[nt]);
    }
  }
  // stage Yoff to LDS (fp32), then vectorized RMW epilogue
#pragma unroll
  for (int nt = 0; nt < 4; ++nt) {
#pragma unroll
    for (int r = 0; r < 4; ++r)
      ys[(wave * 16 + q * 4 + r) * 68 + nt * 16 + lr] = acc[nt][r];
  }
  __syncthreads();
#pragma unroll
  for (int it = 0; it < 2; ++it) {
    int unit = it * 256 + tid;          // t(64) x p8(8)
    int t = unit >> 3, p8 = (unit & 7) * 8;
    float ea_t = ea[t];
    size_t off = (blbase + t) * DSSM + h * HD + p8;
    uint4 yv = *(const uint4*)(y16 + off);
    float4 o0 = *(const float4*)&ys[t * 68 + p8];
    float4 o1 = *(const float4*)&ys[t * 68 + p8 + 4];
    const unsigned int* yu = (const unsigned int*)&yv;
    float oo[8] = {o0.x, o0.y, o0.z, o0.w, o1.x, o1.y, o1.z, o1.w};
    unsigned int ro[4];
#pragma unroll
    for (int d = 0; d < 4; ++d) {
      unsigned short y0 = (unsigned short)(yu[d] & 0xffffu), y1 = (unsigned short)(yu[d] >> 16);
      float v0 = b2f(y0) + ea_t * oo[d * 2 + 0];
      float v1 = b2f(y1) + ea_t * oo[d * 2 + 1];
      ro[d] = (unsigned int)f2b(v0) | ((unsigned int)f2b(v1) << 16);
    }
    *(uint4*)(y16 + off) = make_uint4(ro[0], ro[1], ro[2], ro[3]);
  }
}

// ---------------- gated RMSNorm (vectorized) ----------------
__global__ __launch_bounds__(256) void norm_kernel(
    const unsigned short* __restrict__ y16, const unsigned short* __restrict__ C1,
    const float* __restrict__ normw, unsigned short* __restrict__ yzn)
{
  int bl = blockIdx.x;
  int tid = threadIdx.x;
  int wave = tid >> 6, lane = tid & 63;
  int c8 = tid * 8;
  uint4 yv = *(const uint4*)(y16 + (size_t)bl * DSSM + c8);
  uint4 zv = *(const uint4*)(C1 + (size_t)bl * DPROJ + c8);   // z = first 2048 cols
  const unsigned int* yu = (const unsigned int*)&yv;
  const unsigned int* zu = (const unsigned int*)&zv;
  float vals[8];
  float ss = 0.f;
#pragma unroll
  for (int d = 0; d < 4; ++d) {
    unsigned short y0 = (unsigned short)(yu[d] & 0xffffu), y1 = (unsigned short)(yu[d] >> 16);
    unsigned short z0 = (unsigned short)(zu[d] & 0xffffu), z1 = (unsigned short)(zu[d] >> 16);
    float zf0 = b2f(z0), zf1 = b2f(z1);
    float v0 = b2f(y0) * (zf0 / (1.f + __expf(-zf0)));
    float v1 = b2f(y1) * (zf1 / (1.f + __expf(-zf1)));
    vals[d * 2] = v0; vals[d * 2 + 1] = v1;
    ss += v0 * v0 + v1 * v1;
  }
#pragma unroll
  for (int off = 32; off > 0; off >>= 1) ss += __shfl_down(ss, off);
  __shared__ float red[4];
  if (lane == 0) red[wave] = ss;
  __syncthreads();
  float tot = red[0] + red[1] + red[2] + red[3];
  float scale = rsqrtf(tot * (1.f / 2048.f) + 1e-5f);
  float4 w0 = *(const float4*)(normw + c8);
  float4 w1 = *(const float4*)(normw + c8 + 4);
  float ws[8] = {w0.x, w0.y, w0.z, w0.w, w1.x, w1.y, w1.z, w1.w};
  unsigned int ro[4];
#pragma unroll
  for (int d = 0; d < 4; ++d) {
    unsigned short r0 = f2b(vals[d * 2] * scale * ws[d * 2]);
    unsigned short r1 = f2b(vals[d * 2 + 1] * scale * ws[d * 2 + 1]);
    ro[d] = (unsigned int)r0 | ((unsigned int)r1 << 16);
  }
  *(uint4*)(yzn + (size_t)bl * DSSM + c8) = make_uint4(ro[0], ro[1], ro[2], ro[3]);
}

// ---------------- host launch ----------------
extern "C" void kernel_launch(void* const* d_in, const int* in_sizes, int n_in,
                              void* d_out, int out_size, void* d_ws, size_t ws_size,
                              hipStream_t stream) {
  const float* u      = (const float*)d_in[0];
  const int*   cidx   = (const int*)d_in[1];
  const float* W_in   = (const float*)d_in[2];
  const float* convw  = (const float*)d_in[3];
  const float* convb  = (const float*)d_in[4];
  const float* dtbias = (const float*)d_in[5];
  const float* A_log  = (const float*)d_in[6];
  const float* Dp     = (const float*)d_in[7];
  const float* normw  = (const float*)d_in[8];
  const float* W_out  = (const float*)d_in[9];

  char* w = (char*)d_ws;
  size_t off = 0;
  auto alloc = [&](size_t bytes) { char* p = w + off; off += (bytes + 255) & ~(size_t)255; return p; };
  unsigned short* u16     = (unsigned short*)alloc((size_t)BLTOT * DMODEL * 2);
  unsigned short* Win16   = (unsigned short*)alloc((size_t)DPROJ * DMODEL * 2);
  unsigned short* Wout16  = (unsigned short*)alloc((size_t)DMODEL * DSSM * 2);
  unsigned short* C1      = (unsigned short*)alloc((size_t)BLTOT * DPROJ * 2);
  unsigned short* Bg16    = (unsigned short*)alloc((size_t)BLTOT * DST * 2);
  unsigned short* Cg16    = (unsigned short*)alloc((size_t)BLTOT * DST * 2);
  float*          dtb     = (float*)alloc((size_t)BLTOT * NH * 4);
  float*          acumb   = (float*)alloc((size_t)BB * NC * NH * CS * 4);
  unsigned short* y16     = (unsigned short*)alloc((size_t)BLTOT * DSSM * 2);
  unsigned short* statesb = (unsigned short*)alloc((size_t)BB * NC * NH * DST * HD * 2);
  float*          cdb     = (float*)alloc((size_t)BB * NC * NH * 4);
  unsigned short* yzn     = (unsigned short*)alloc((size_t)BLTOT * DSSM * 2);

  const int na4 = BLTOT * DMODEL / 4, nb4 = DPROJ * DMODEL / 4, nc4 = DMODEL * DSSM / 4;
  cvt3_kernel<<<(na4 + nb4 + nc4 + 255) / 256, 256, 0, stream>>>(
      u, u16, na4, W_in, Win16, nb4, W_out, Wout16, nc4);

  // zxbcdt = u @ W_in^T (bf16 out) — single-buffer m97 (r0-exact; best measured 54.5 µs)
  gemm_bt<128, 1, 0><<<dim3(BLTOT / 128, (DPROJ + 127) / 128), 256, 0, stream>>>(
      u16, Win16, C1, BLTOT, DPROJ, DMODEL, DPROJ);
  convBC_kernel<<<BLTOT / 16, 256, 0, stream>>>(C1, cidx, convw, convb, dtbias, Bg16, Cg16, dtb);
  d1_intra<<<BB * NC * NH, 256, 0, stream>>>(C1, cidx, convw, convb, Bg16, Cg16, dtb,
                                             A_log, Dp, y16, statesb, cdb, acumb);
  d2_scan<<<BB * NH * 32, 256, 0, stream>>>(statesb, cdb);
  d3_inter<<<BB * NC * NH, 256, 0, stream>>>(Cg16, statesb, acumb, y16);
  norm_kernel<<<BLTOT, 256, 0, stream>>>(y16, C1, normw, yzn);
  // out = yzn @ W_out^T (fp32 out) — double-buffered (grid-limited 2/CU; r5 A/B: −3.6 µs)
  gemm_bt<64, 0, 1><<<dim3(BLTOT / 128, DMODEL / 64), 256, 0, stream>>>(
      yzn, Wout16, (float*)d_out, BLTOT, DMODEL, DSSM, DMODEL);
}

// Round 7
// 254.672 us; speedup vs baseline: 1.0507x; 1.0066x over previous
//
#include <hip/hip_runtime.h>

// ---- problem constants ----
#define BB 2
#define LL 2048
#define DMODEL 1024
#define DSSM 2048
#define NH 32
#define HD 64
#define DST 128
#define CONVD 2304
#define DPROJ 4384
#define CS 64               // SSD chunk size (rechunked; math is exact)
#define NC 32               // LL/CS
#define BLTOT (BB*LL)       // 4096

typedef short v8s __attribute__((ext_vector_type(8)));
typedef float v4f __attribute__((ext_vector_type(4)));

__device__ __forceinline__ float b2f(unsigned short h) {
  union { unsigned int u; float f; } v; v.u = ((unsigned int)h) << 16; return v.f;
}
__device__ __forceinline__ unsigned short f2b(float f) {
  union { float f; unsigned int u; } v; v.f = f;
  unsigned int u = v.u;
  return (unsigned short)((u + 0x7fffu + ((u >> 16) & 1u)) >> 16);
}
__device__ __forceinline__ v4f mfma16(v8s a, v8s b, v4f c) {
  return __builtin_amdgcn_mfma_f32_16x16x32_bf16(a, b, c, 0, 0, 0);
}
// async global->LDS, 16B per lane; LDS dest = wave-uniform base + lane*16
__device__ __forceinline__ void gl_lds16(const unsigned short* g, unsigned short* l) {
  __builtin_amdgcn_global_load_lds(
      (const __attribute__((address_space(1))) void*)(g),
      (__attribute__((address_space(3))) void*)(l), 16, 0, 0);
}

// ---------------- fused fp32 -> bf16 conversion (3 tensors, 1 launch) ----------------
__global__ __launch_bounds__(256) void cvt3_kernel(
    const float* __restrict__ a, unsigned short* __restrict__ oa, int na4,
    const float* __restrict__ b, unsigned short* __restrict__ ob, int nb4,
    const float* __restrict__ c, unsigned short* __restrict__ oc, int nc4)
{
  int i = blockIdx.x * 256 + threadIdx.x;
  const float* src; unsigned short* dst; int j;
  if (i < na4) { src = a; dst = oa; j = i; }
  else if (i < na4 + nb4) { src = b; dst = ob; j = i - na4; }
  else if (i < na4 + nb4 + nc4) { src = c; dst = oc; j = i - na4 - nb4; }
  else return;
  float4 v = ((const float4*)src)[j];
  ushort4 o;
  o.x = f2b(v.x); o.y = f2b(v.y); o.z = f2b(v.z); o.w = f2b(v.w);
  ((ushort4*)dst)[j] = o;
}

// ---------------- bf16 GEMM: 128 x TN tile, 256 threads ----------------
// DBUF=0: exact r0 single-buffer m97 loop — best for gemm1 (TN=128): 32 KB LDS keeps
//   4+ blocks/CU; cross-block wave overlap hides the pre-barrier drain (measured:
//   every pipelining variant at TN=128 was neutral/negative — r1 8-phase, r5 dbuf).
// DBUF=1: stage-early double-buffer — best for gemm2 (TN=64): grid-limited 2 blocks/CU,
//   dbuf LDS (48 KB) still allows 3/CU so the pipeline is free (r5 A/B: −3.6 µs).
template<int TN, int OUT_BF16, int DBUF>
__global__ __launch_bounds__(256) void gemm_bt(
    const unsigned short* __restrict__ A, const unsigned short* __restrict__ Bt,
    void* __restrict__ Cout, int M, int N, int K, int ldc)
{
  constexpr int NT = TN / 32;                 // n-tiles per wave
  constexpr int NB = DBUF ? 2 : 1;
  const int bm = blockIdx.x, bn = blockIdx.y;
  const int tid = threadIdx.x;
  const int wave = tid >> 6, lane = tid & 63;
  const int wm = wave & 1, wn = wave >> 1;
  const int q = lane >> 4, lr = lane & 15;

  __shared__ __align__(16) unsigned short As[NB][128 * 64];
  __shared__ __align__(16) unsigned short Bs[NB][TN * 64];

  v4f acc[4][NT];
#pragma unroll
  for (int i = 0; i < 4; i++)
#pragma unroll
    for (int j = 0; j < NT; j++) acc[i][j] = v4f{0.f, 0.f, 0.f, 0.f};

  const int lrow = lane >> 3;                 // 0..7 (row within 8-row group)
  const int gchunk = (lane & 7) ^ lrow;       // swizzled source 16B-chunk

#define STAGE_TILE(bufi, k0) do {                                              \
    _Pragma("unroll")                                                          \
    for (int it = 0; it < 4; ++it) {                                           \
      int r = wave * 32 + it * 8 + lrow;                                       \
      gl_lds16(A + (size_t)(bm * 128 + r) * K + (k0) + gchunk * 8,             \
               &As[bufi][(wave * 32 + it * 8) * 64]);                          \
    }                                                                          \
    _Pragma("unroll")                                                          \
    for (int it = 0; it < TN / 32; ++it) {                                     \
      int rloc = wave * (TN / 4) + it * 8;                                     \
      int rb = bn * TN + rloc + lrow; if (rb >= N) rb = N - 1;                 \
      gl_lds16(Bt + (size_t)rb * K + (k0) + gchunk * 8, &Bs[bufi][rloc * 64]); \
    }                                                                          \
  } while (0)

#define COMPUTE_TILE(bufi) do {                                                \
    const unsigned short* __restrict__ Ab = As[bufi];                          \
    const unsigned short* __restrict__ Bb = Bs[bufi];                          \
    _Pragma("unroll")                                                          \
    for (int ks = 0; ks < 64; ks += 32) {                                      \
      const int c0 = (ks >> 3) + q;                                            \
      v8s af[4], bf[NT];                                                       \
      _Pragma("unroll")                                                        \
      for (int mt = 0; mt < 4; ++mt) {                                         \
        int r = wm * 64 + mt * 16 + lr;                                        \
        af[mt] = *(const v8s*)&Ab[r * 64 + ((c0 ^ (r & 7)) << 3)];             \
      }                                                                        \
      _Pragma("unroll")                                                        \
      for (int nt = 0; nt < NT; ++nt) {                                        \
        int r = wn * (TN / 2) + nt * 16 + lr;                                  \
        bf[nt] = *(const v8s*)&Bb[r * 64 + ((c0 ^ (r & 7)) << 3)];             \
      }                                                                        \
      _Pragma("unroll")                                                        \
      for (int mt = 0; mt < 4; ++mt)                                           \
        _Pragma("unroll")                                                      \
        for (int nt = 0; nt < NT; ++nt)                                        \
          acc[mt][nt] = mfma16(af[mt], bf[nt], acc[mt][nt]);                   \
    }                                                                          \
  } while (0)

#define WAIT_BARRIER() do {                                                    \
    __builtin_amdgcn_sched_barrier(0);                                         \
    asm volatile("s_waitcnt vmcnt(0) lgkmcnt(0)\ns_barrier" ::: "memory");     \
  } while (0)

  if constexpr (DBUF == 0) {
    // r0-exact single-buffer loop
    for (int k0 = 0; k0 < K; k0 += 64) {
      __syncthreads();
      STAGE_TILE(0, k0);
      __syncthreads();
      COMPUTE_TILE(0);
    }
  } else {
    const int nkt = K >> 6;
    STAGE_TILE(0, 0);
    WAIT_BARRIER();
    for (int kt = 0; kt < nkt; ++kt) {
      const int cb = kt & 1;
      if (kt + 1 < nkt) STAGE_TILE(cb ^ 1, (kt + 1) << 6);
      COMPUTE_TILE(cb);
      if (kt + 1 < nkt) WAIT_BARRIER();
    }
  }
#undef STAGE_TILE
#undef COMPUTE_TILE
#undef WAIT_BARRIER

#pragma unroll
  for (int mt = 0; mt < 4; ++mt) {
#pragma unroll
    for (int nt = 0; nt < NT; ++nt) {
      int row = bm * 128 + wm * 64 + mt * 16 + q * 4;
      int col = bn * TN + wn * (TN / 2) + nt * 16 + lr;
      if (col < N) {
#pragma unroll
        for (int r = 0; r < 4; ++r) {
          float v = acc[mt][nt][r];
          if (OUT_BF16) ((unsigned short*)Cout)[(size_t)(row + r) * ldc + col] = f2b(v);
          else          ((float*)Cout)[(size_t)(row + r) * ldc + col] = v;
        }
      }
    }
  }
}

// ---------------- slim tree conv: B/C cols + dt softplus only ----------------
// Now also emits B TRANSPOSED (BgT[n][token], 1 MB, L2-resident) so d1 can build
// its weighted B^T tile without the 8-way-bank-conflict LDS transpose.
__global__ __launch_bounds__(256) void convBC_kernel(
    const unsigned short* __restrict__ C1, const int* __restrict__ cidx,
    const float* __restrict__ convw, const float* __restrict__ convb,
    const float* __restrict__ dtbias,
    unsigned short* __restrict__ Bg16, unsigned short* __restrict__ Cg16,
    unsigned short* __restrict__ BgT16, float* __restrict__ dtb)
{
  int bl0 = blockIdx.x * 16;           // 16 tokens per block (grid = BLTOT/16 = 256)
  int b = bl0 >> 11;
  int tid = threadIdx.x;
  __shared__ int idxs[64];
  if (tid < 64) {
    int tk = tid >> 2, k = tid & 3;
    idxs[tid] = cidx[b * (4 * LL) + (((bl0 + tk) & 2047) * 4) + k];
  }
  __syncthreads();
  const float4* cw4 = (const float4*)convw;
  int quad = tid & 63;                 // 64 quads cover B/C's 256 cols
  int relc = DSSM + quad * 4;          // xBC-relative col (B/C region)
  float4 w0 = cw4[relc], w1 = cw4[relc + 1], w2 = cw4[relc + 2], w3 = cw4[relc + 3];
  float4 cb = *(const float4*)(convb + relc);
  int tk0 = (tid >> 6) * 4;
  int cc = relc - DSSM;
  unsigned short btc[4][4];            // [col][token] accum for transposed B write
#pragma unroll
  for (int tt = 0; tt < 4; ++tt) {
    int tk = tk0 + tt;
    int bl = bl0 + tk;
    ushort4 rv[4];
#pragma unroll
    for (int k = 0; k < 4; ++k) {
      int iv = idxs[tk * 4 + k];
      rv[k] = (iv > 0) ? *(const ushort4*)(C1 + (size_t)(b * LL + iv - 1) * DPROJ + DSSM + relc)
                       : make_ushort4(0, 0, 0, 0);
    }
    float a0 = cb.x + b2f(rv[0].x) * w0.x + b2f(rv[1].x) * w0.y + b2f(rv[2].x) * w0.z + b2f(rv[3].x) * w0.w;
    float a1 = cb.y + b2f(rv[0].y) * w1.x + b2f(rv[1].y) * w1.y + b2f(rv[2].y) * w1.z + b2f(rv[3].y) * w1.w;
    float a2 = cb.z + b2f(rv[0].z) * w2.x + b2f(rv[1].z) * w2.y + b2f(rv[2].z) * w2.z + b2f(rv[3].z) * w2.w;
    float a3 = cb.w + b2f(rv[0].w) * w3.x + b2f(rv[1].w) * w3.y + b2f(rv[2].w) * w3.z + b2f(rv[3].w) * w3.w;
    ushort4 o;
    o.x = f2b(a0 / (1.f + __expf(-a0)));
    o.y = f2b(a1 / (1.f + __expf(-a1)));
    o.z = f2b(a2 / (1.f + __expf(-a2)));
    o.w = f2b(a3 / (1.f + __expf(-a3)));
    if (cc < DST) {
      *(ushort4*)(Bg16 + (size_t)bl * DST + cc) = o;
      btc[0][tt] = o.x; btc[1][tt] = o.y; btc[2][tt] = o.z; btc[3][tt] = o.w;
    } else {
      *(ushort4*)(Cg16 + (size_t)bl * DST + (cc - DST)) = o;
    }
  }
  if (cc < DST) {
#pragma unroll
    for (int c = 0; c < 4; ++c)
      *(ushort4*)(BgT16 + (size_t)(cc + c) * BLTOT + bl0 + tk0) =
          make_ushort4(btc[c][0], btc[c][1], btc[c][2], btc[c][3]);
  }
  for (int u = tid; u < 16 * NH; u += 256) {   // 16 tokens x 32 heads
    int tk = u >> 5, hh = u & 31;
    int bl = bl0 + tk;
    float raw = b2f(C1[(size_t)bl * DPROJ + DSSM + CONVD + hh]) + dtbias[hh];
    float dtv = (raw > 20.f) ? raw : log1pf(__expf(raw));
    dtb[(size_t)bl * NH + hh] = dtv;
  }
}

// ---------------- SSD intra-chunk: x-conv fused + Yd + D*x, states^T, decays --------
// BTw now staged directly from BgT (transposed-B global, L2-hot) with dec*dt applied
// in registers — replaces the old 32-scalar-read 8-way-bank-conflict LDS transpose.
// Bit-identical math (same bf16 inputs, same mul/round chain).
__global__ __launch_bounds__(256) void d1_intra(
    const unsigned short* __restrict__ C1, const int* __restrict__ cidx,
    const float* __restrict__ convw, const float* __restrict__ convb,
    const unsigned short* __restrict__ Bg16,
    const unsigned short* __restrict__ Cg16,
    const unsigned short* __restrict__ BgT16, const float* __restrict__ dtb,
    const float* __restrict__ A_log, const float* __restrict__ Dp,
    unsigned short* __restrict__ y16, unsigned short* __restrict__ statesb,
    float* __restrict__ cdb, float* __restrict__ acumb)
{
  int gid = blockIdx.x;
  int h = gid & 31, ci = (gid >> 5) & 31, b = gid >> 10;
  int tid = threadIdx.x, wave = tid >> 6, lane = tid & 63, q = lane >> 4, lr = lane & 15;

  __shared__ __align__(16) unsigned short BnG[CS * 136];  // B[s][n]; reused as G[t][s] (stride 72)
  __shared__ __align__(16) unsigned short BTw[DST * 72];  // B^T[n][s] * dec[s] * dt[s]
  __shared__ __align__(16) unsigned short xT[HD * 72];    // x^T[p][s]  (no dt)
  __shared__ float dt_s[CS], ac_s[CS], dec_s[CS];
  __shared__ int idxs[CS * 4];          // tree indices for this chunk's 64 tokens
  __shared__ float wls[HD * 4];         // conv weights for this head's 64 x-cols
  __shared__ float bls[HD];             // conv bias

  const size_t blbase = (size_t)b * LL + ci * CS;
  const size_t chbase = (size_t)(b * NC + ci) * NH + h;
  float Ah = -__expf(A_log[h]);

  // wave0: dt load + shuffle inclusive scan (no barriers)
  if (wave == 0) {
    float d = dtb[(blbase + lane) * NH + h];
    float a = d * Ah;
#pragma unroll
    for (int off = 1; off < 64; off <<= 1) {
      float u = __shfl_up(a, off, 64);
      if (lane >= off) a += u;
    }
    float tot = __shfl(a, 63, 64);
    dt_s[lane] = d;
    ac_s[lane] = a;
    dec_s[lane] = __expf(tot - a);
    acumb[chbase * CS + lane] = a;
    if (lane == 0) cdb[chbase] = __expf(tot);
  }

  // stage B tile (64 x 128)
#pragma unroll
  for (int g = 0; g < 8; ++g) {
    int f = g * 256 + tid;              // s(64) x n-quads(32)
    int s = f >> 5, c4 = (f & 31) * 4;
    *(ushort4*)&BnG[s * 136 + c4] = *(const ushort4*)(Bg16 + (blbase + s) * DST + c4);
  }
  // stage tree indices + conv weights/bias for this head's x-cols
  {
    int s = tid >> 2, k = tid & 3;      // 256 threads = 64 tokens x 4 taps
    idxs[tid] = cidx[b * (4 * LL) + (ci * CS + s) * 4 + k];
  }
  if (tid < HD) *(float4*)&wls[tid * 4] = *(const float4*)(convw + (h * HD + tid) * 4);
  if (tid < HD / 4) *(float4*)&bls[tid * 4] = *(const float4*)(convb + h * HD + tid * 4);
  __syncthreads();                      // barrier 1 (dt_s/dec_s ready)

  // BTw[n][s] = BgT[n][tok] * dec[s] * dt[s]  (reg-staged, conflict-free)
#pragma unroll
  for (int g = 0; g < 8; ++g) {
    int f = g * 256 + tid;              // n(128) x s-quads(16)
    int n = f >> 4, s4 = (f & 15) * 4;
    ushort4 bv = *(const ushort4*)(BgT16 + (size_t)n * BLTOT + blbase + s4);
    ushort4 o;
    o.x = f2b(b2f(bv.x) * dec_s[s4 + 0] * dt_s[s4 + 0]);
    o.y = f2b(b2f(bv.y) * dec_s[s4 + 1] * dt_s[s4 + 1]);
    o.z = f2b(b2f(bv.z) * dec_s[s4 + 2] * dt_s[s4 + 2]);
    o.w = f2b(b2f(bv.w) * dec_s[s4 + 3] * dt_s[s4 + 3]);
    *(ushort4*)&BTw[n * 72 + s4] = o;
  }

  // S[t][s] = sum_n C[t][n] * B[s][n]  (C A-fragments direct from global)
  v4f accS[4];
#pragma unroll
  for (int i = 0; i < 4; i++) accS[i] = v4f{0.f, 0.f, 0.f, 0.f};
#pragma unroll
  for (int ks = 0; ks < 128; ks += 32) {
    v8s a = *(const v8s*)(Cg16 + (blbase + wave * 16 + lr) * DST + ks + q * 8);
#pragma unroll
    for (int si = 0; si < 4; ++si) {
      v8s bb = *(const v8s*)&BnG[(si * 16 + lr) * 136 + ks + q * 8];
      accS[si] = mfma16(a, bb, accS[si]);
    }
  }

  // fused x tree-conv -> xT[p][s] (writes complete before barrier 2; read after barrier 3)
#pragma unroll
  for (int g = 0; g < 4; ++g) {
    int f = g * 256 + tid;              // s(64) x p-quads(16)
    int s = f >> 4, p4 = (f & 15) * 4;
    ushort4 rv[4];
#pragma unroll
    for (int k = 0; k < 4; ++k) {
      int iv = idxs[s * 4 + k];
      rv[k] = (iv > 0) ? *(const ushort4*)(C1 + (size_t)(b * LL + iv - 1) * DPROJ + DSSM + h * HD + p4)
                       : make_ushort4(0, 0, 0, 0);
    }
    float4 w0 = *(const float4*)&wls[(p4 + 0) * 4];
    float4 w1 = *(const float4*)&wls[(p4 + 1) * 4];
    float4 w2 = *(const float4*)&wls[(p4 + 2) * 4];
    float4 w3 = *(const float4*)&wls[(p4 + 3) * 4];
    float a0 = bls[p4 + 0] + b2f(rv[0].x) * w0.x + b2f(rv[1].x) * w0.y + b2f(rv[2].x) * w0.z + b2f(rv[3].x) * w0.w;
    float a1 = bls[p4 + 1] + b2f(rv[0].y) * w1.x + b2f(rv[1].y) * w1.y + b2f(rv[2].y) * w1.z + b2f(rv[3].y) * w1.w;
    float a2 = bls[p4 + 2] + b2f(rv[0].z) * w2.x + b2f(rv[1].z) * w2.y + b2f(rv[2].z) * w2.z + b2f(rv[3].z) * w2.w;
    float a3 = bls[p4 + 3] + b2f(rv[0].w) * w3.x + b2f(rv[1].w) * w3.y + b2f(rv[2].w) * w3.z + b2f(rv[3].w) * w3.w;
    xT[(p4 + 0) * 72 + s] = f2b(a0 / (1.f + __expf(-a0)));
    xT[(p4 + 1) * 72 + s] = f2b(a1 / (1.f + __expf(-a1)));
    xT[(p4 + 2) * 72 + s] = f2b(a2 / (1.f + __expf(-a2)));
    xT[(p4 + 3) * 72 + s] = f2b(a3 / (1.f + __expf(-a3)));
  }
  __syncthreads();                      // barrier 2 (BnG reads done, xT/BTw written)

  // G[t][s] = S * exp(Acum[t]-Acum[s]) * dt[s], masked s<=t; stride 72
  {
    int tbase = wave * 16 + q * 4;
#pragma unroll
    for (int si = 0; si < 4; ++si) {
      int s = si * 16 + lr;
      float ds = dt_s[s], as = ac_s[s];
#pragma unroll
      for (int r = 0; r < 4; ++r) {
        int tt = tbase + r;
        float g = 0.f;
        if (s <= tt) g = accS[si][r] * __expf(ac_s[tt] - as) * ds;
        BnG[tt * 72 + s] = f2b(g);
      }
    }
  }
  __syncthreads();                      // barrier 3

  // Yd[t][p] = G @ x ; states^T[p][n] = sum_s xT[p][s]*BTw[n][s]
  v4f accY[4], accPT[4][2];
#pragma unroll
  for (int i = 0; i < 4; i++) {
    accY[i] = v4f{0.f,0.f,0.f,0.f};
    accPT[i][0] = v4f{0.f,0.f,0.f,0.f};
    accPT[i][1] = v4f{0.f,0.f,0.f,0.f};
  }
  int nw = wave * 32;                   // wave covers n in [nw, nw+32)
#pragma unroll
  for (int ks = 0; ks < 64; ks += 32) {
    v8s xf[4];
#pragma unroll
    for (int i = 0; i < 4; ++i) xf[i] = *(const v8s*)&xT[(i * 16 + lr) * 72 + ks + q * 8];
    v8s aG  = *(const v8s*)&BnG[(wave * 16 + lr) * 72 + ks + q * 8];
    v8s bw0 = *(const v8s*)&BTw[(nw + lr) * 72 + ks + q * 8];
    v8s bw1 = *(const v8s*)&BTw[(nw + 16 + lr) * 72 + ks + q * 8];
#pragma unroll
    for (int nt = 0; nt < 4; ++nt) {
      accY[nt] = mfma16(aG, xf[nt], accY[nt]);
      accPT[nt][0] = mfma16(xf[nt], bw0, accPT[nt][0]);
      accPT[nt][1] = mfma16(xf[nt], bw1, accPT[nt][1]);
    }
  }

  // epilogue: y = Yd + D*x  (x from LDS xT)
  float Dh = Dp[h];
#pragma unroll
  for (int nt = 0; nt < 4; ++nt) {
    int p = nt * 16 + lr;
#pragma unroll
    for (int r = 0; r < 4; ++r) {
      int t = wave * 16 + q * 4 + r;
      float xv = b2f(xT[p * 72 + t]);
      y16[(blbase + t) * DSSM + h * HD + p] = f2b(accY[nt][r] + Dh * xv);
    }
  }
  // epilogue: states^T  (layout [p][n], p<HD rows, n<DST cols)
  size_t sbase = chbase * (DST * HD);
#pragma unroll
  for (int mt = 0; mt < 4; ++mt) {
#pragma unroll
    for (int nt = 0; nt < 2; ++nt) {
      int n = nw + nt * 16 + lr;
#pragma unroll
      for (int r = 0; r < 4; ++r) {
        int p = mt * 16 + q * 4 + r;
        statesb[sbase + (size_t)p * DST + n] = f2b(accPT[mt][nt][r]);
      }
    }
  }
}

// ---------------- state passing: vectorized (ushort4) register scan ----------------
// 512 blocks: (b,h) x 8 segments; 4 contiguous elems/thread over 32 chunks.
// 4x fewer VMEM instructions than the scalar version; same bytes, same math.
__global__ __launch_bounds__(256) void d2_scan(
    unsigned short* __restrict__ statesb, const float* __restrict__ cdb)
{
  int g = blockIdx.x;
  int seg = g & 7, bh = g >> 3;
  int b = bh >> 5, h = bh & 31;
  int e4 = seg * 1024 + threadIdx.x * 4;   // 0..8188, 4 elems/thread
  const size_t cstride = (size_t)NH * DST * HD;
  size_t base = ((size_t)(b * NC) * NH + h) * (DST * HD) + e4;
  ushort4 st[NC];
#pragma unroll
  for (int ci = 0; ci < NC; ++ci) st[ci] = *(const ushort4*)(statesb + base + ci * cstride);
  float r0 = 0.f, r1 = 0.f, r2 = 0.f, r3 = 0.f;
#pragma unroll
  for (int ci = 0; ci < NC; ++ci) {
    float cd = cdb[(b * NC + ci) * NH + h];
    *(ushort4*)(statesb + base + ci * cstride) =
        make_ushort4(f2b(r0), f2b(r1), f2b(r2), f2b(r3));   // prev entering chunk ci
    r0 = r0 * cd + b2f(st[ci].x);
    r1 = r1 * cd + b2f(st[ci].y);
    r2 = r2 * cd + b2f(st[ci].z);
    r3 = r3 * cd + b2f(st[ci].w);
  }
}

// ---------------- SSD inter-chunk: Y += exp(Acum[t]) * C @ prev^T ----------------
// prev stored [p][n] -> straight vector staging; D*x already folded into d1
__global__ __launch_bounds__(256) void d3_inter(
    const unsigned short* __restrict__ Cg16,
    const unsigned short* __restrict__ statesb, const float* __restrict__ acumb,
    unsigned short* __restrict__ y16)
{
  int gid = blockIdx.x;
  int h = gid & 31, ci = (gid >> 5) & 31, b = gid >> 10;
  int tid = threadIdx.x, wave = tid >> 6, lane = tid & 63, q = lane >> 4, lr = lane & 15;
  __shared__ __align__(16) unsigned short pT[HD * 136];   // prev^T[p][n]
  __shared__ __align__(16) float ys[CS * 68];             // y-stage (fp32)
  __shared__ float ea[CS];
  const size_t blbase = (size_t)b * LL + ci * CS;
  const size_t chbase = (size_t)(b * NC + ci) * NH + h;
  if (tid < CS) ea[tid] = __expf(acumb[chbase * CS + tid]);
  size_t sbase = chbase * (DST * HD);
  // stage prev^T: plain vector copy (64 rows x 128 cols)
#pragma unroll
  for (int g = 0; g < 8; ++g) {
    int f = g * 256 + tid;              // p(64) x n-quads(32)
    int p = f >> 5, c4 = (f & 31) * 4;
    *(ushort4*)&pT[p * 136 + c4] = *(const ushort4*)(statesb + sbase + (size_t)p * DST + c4);
  }
  __syncthreads();
  v4f acc[4];
#pragma unroll
  for (int i = 0; i < 4; i++) acc[i] = v4f{0.f, 0.f, 0.f, 0.f};
#pragma unroll
  for (int ks = 0; ks < 128; ks += 32) {
    v8s a = *(const v8s*)(Cg16 + (blbase + wave * 16 + lr) * DST + ks + q * 8);
#pragma unroll
    for (int nt = 0; nt < 4; ++nt) {
      v8s bb = *(const v8s*)&pT[(nt * 16 + lr) * 136 + ks + q * 8];
      acc[nt] = mfma16(a, bb, acc[nt]);
    }
  }
  // stage Yoff to LDS (fp32), then vectorized RMW epilogue
#pragma unroll
  for (int nt = 0; nt < 4; ++nt) {
#pragma unroll
    for (int r = 0; r < 4; ++r)
      ys[(wave * 16 + q * 4 + r) * 68 + nt * 16 + lr] = acc[nt][r];
  }
  __syncthreads();
#pragma unroll
  for (int it = 0; it < 2; ++it) {
    int unit = it * 256 + tid;          // t(64) x p8(8)
    int t = unit >> 3, p8 = (unit & 7) * 8;
    float ea_t = ea[t];
    size_t off = (blbase + t) * DSSM + h * HD + p8;
    uint4 yv = *(const uint4*)(y16 + off);
    float4 o0 = *(const float4*)&ys[t * 68 + p8];
    float4 o1 = *(const float4*)&ys[t * 68 + p8 + 4];
    const unsigned int* yu = (const unsigned int*)&yv;
    float oo[8] = {o0.x, o0.y, o0.z, o0.w, o1.x, o1.y, o1.z, o1.w};
    unsigned int ro[4];
#pragma unroll
    for (int d = 0; d < 4; ++d) {
      unsigned short y0 = (unsigned short)(yu[d] & 0xffffu), y1 = (unsigned short)(yu[d] >> 16);
      float v0 = b2f(y0) + ea_t * oo[d * 2 + 0];
      float v1 = b2f(y1) + ea_t * oo[d * 2 + 1];
      ro[d] = (unsigned int)f2b(v0) | ((unsigned int)f2b(v1) << 16);
    }
    *(uint4*)(y16 + off) = make_uint4(ro[0], ro[1], ro[2], ro[3]);
  }
}

// ---------------- gated RMSNorm (vectorized) ----------------
__global__ __launch_bounds__(256) void norm_kernel(
    const unsigned short* __restrict__ y16, const unsigned short* __restrict__ C1,
    const float* __restrict__ normw, unsigned short* __restrict__ yzn)
{
  int bl = blockIdx.x;
  int tid = threadIdx.x;
  int wave = tid >> 6, lane = tid & 63;
  int c8 = tid * 8;
  uint4 yv = *(const uint4*)(y16 + (size_t)bl * DSSM + c8);
  uint4 zv = *(const uint4*)(C1 + (size_t)bl * DPROJ + c8);   // z = first 2048 cols
  const unsigned int* yu = (const unsigned int*)&yv;
  const unsigned int* zu = (const unsigned int*)&zv;
  float vals[8];
  float ss = 0.f;
#pragma unroll
  for (int d = 0; d < 4; ++d) {
    unsigned short y0 = (unsigned short)(yu[d] & 0xffffu), y1 = (unsigned short)(yu[d] >> 16);
    unsigned short z0 = (unsigned short)(zu[d] & 0xffffu), z1 = (unsigned short)(zu[d] >> 16);
    float zf0 = b2f(z0), zf1 = b2f(z1);
    float v0 = b2f(y0) * (zf0 / (1.f + __expf(-zf0)));
    float v1 = b2f(y1) * (zf1 / (1.f + __expf(-zf1)));
    vals[d * 2] = v0; vals[d * 2 + 1] = v1;
    ss += v0 * v0 + v1 * v1;
  }
#pragma unroll
  for (int off = 32; off > 0; off >>= 1) ss += __shfl_down(ss, off);
  __shared__ float red[4];
  if (lane == 0) red[wave] = ss;
  __syncthreads();
  float tot = red[0] + red[1] + red[2] + red[3];
  float scale = rsqrtf(tot * (1.f / 2048.f) + 1e-5f);
  float4 w0 = *(const float4*)(normw + c8);
  float4 w1 = *(const float4*)(normw + c8 + 4);
  float ws[8] = {w0.x, w0.y, w0.z, w0.w, w1.x, w1.y, w1.z, w1.w};
  unsigned int ro[4];
#pragma unroll
  for (int d = 0; d < 4; ++d) {
    unsigned short r0 = f2b(vals[d * 2] * scale * ws[d * 2]);
    unsigned short r1 = f2b(vals[d * 2 + 1] * scale * ws[d * 2 + 1]);
    ro[d] = (unsigned int)r0 | ((unsigned int)r1 << 16);
  }
  *(uint4*)(yzn + (size_t)bl * DSSM + c8) = make_uint4(ro[0], ro[1], ro[2], ro[3]);
}

// ---------------- host launch ----------------
extern "C" void kernel_launch(void* const* d_in, const int* in_sizes, int n_in,
                              void* d_out, int out_size, void* d_ws, size_t ws_size,
                              hipStream_t stream) {
  const float* u      = (const float*)d_in[0];
  const int*   cidx   = (const int*)d_in[1];
  const float* W_in   = (const float*)d_in[2];
  const float* convw  = (const float*)d_in[3];
  const float* convb  = (const float*)d_in[4];
  const float* dtbias = (const float*)d_in[5];
  const float* A_log  = (const float*)d_in[6];
  const float* Dp     = (const float*)d_in[7];
  const float* normw  = (const float*)d_in[8];
  const float* W_out  = (const float*)d_in[9];

  char* w = (char*)d_ws;
  size_t off = 0;
  auto alloc = [&](size_t bytes) { char* p = w + off; off += (bytes + 255) & ~(size_t)255; return p; };
  unsigned short* u16     = (unsigned short*)alloc((size_t)BLTOT * DMODEL * 2);
  unsigned short* Win16   = (unsigned short*)alloc((size_t)DPROJ * DMODEL * 2);
  unsigned short* Wout16  = (unsigned short*)alloc((size_t)DMODEL * DSSM * 2);
  unsigned short* C1      = (unsigned short*)alloc((size_t)BLTOT * DPROJ * 2);
  unsigned short* Bg16    = (unsigned short*)alloc((size_t)BLTOT * DST * 2);
  unsigned short* Cg16    = (unsigned short*)alloc((size_t)BLTOT * DST * 2);
  unsigned short* BgT16   = (unsigned short*)alloc((size_t)DST * BLTOT * 2);
  float*          dtb     = (float*)alloc((size_t)BLTOT * NH * 4);
  float*          acumb   = (float*)alloc((size_t)BB * NC * NH * CS * 4);
  unsigned short* y16     = (unsigned short*)alloc((size_t)BLTOT * DSSM * 2);
  unsigned short* statesb = (unsigned short*)alloc((size_t)BB * NC * NH * DST * HD * 2);
  float*          cdb     = (float*)alloc((size_t)BB * NC * NH * 4);
  unsigned short* yzn     = (unsigned short*)alloc((size_t)BLTOT * DSSM * 2);

  const int na4 = BLTOT * DMODEL / 4, nb4 = DPROJ * DMODEL / 4, nc4 = DMODEL * DSSM / 4;
  cvt3_kernel<<<(na4 + nb4 + nc4 + 255) / 256, 256, 0, stream>>>(
      u, u16, na4, W_in, Win16, nb4, W_out, Wout16, nc4);

  // zxbcdt = u @ W_in^T (bf16 out) — single-buffer m97 (best measured 54.5 µs)
  gemm_bt<128, 1, 0><<<dim3(BLTOT / 128, (DPROJ + 127) / 128), 256, 0, stream>>>(
      u16, Win16, C1, BLTOT, DPROJ, DMODEL, DPROJ);
  convBC_kernel<<<BLTOT / 16, 256, 0, stream>>>(C1, cidx, convw, convb, dtbias,
                                                Bg16, Cg16, BgT16, dtb);
  d1_intra<<<BB * NC * NH, 256, 0, stream>>>(C1, cidx, convw, convb, Bg16, Cg16, BgT16,
                                             dtb, A_log, Dp, y16, statesb, cdb, acumb);
  d2_scan<<<BB * NH * 8, 256, 0, stream>>>(statesb, cdb);
  d3_inter<<<BB * NC * NH, 256, 0, stream>>>(Cg16, statesb, acumb, y16);
  norm_kernel<<<BLTOT, 256, 0, stream>>>(y16, C1, normw, yzn);
  // out = yzn @ W_out^T (fp32 out) — double-buffered (grid-limited; r5 A/B: −3.6 µs)
  gemm_bt<64, 0, 1><<<dim3(BLTOT / 128, DMODEL / 64), 256, 0, stream>>>(
      yzn, Wout16, (float*)d_out, BLTOT, DMODEL, DSSM, DMODEL);
}

// Round 8
// 254.368 us; speedup vs baseline: 1.0519x; 1.0012x over previous
//
#include <hip/hip_runtime.h>

// ---- problem constants ----
#define BB 2
#define LL 2048
#define DMODEL 1024
#define DSSM 2048
#define NH 32
#define HD 64
#define DST 128
#define CONVD 2304
#define DPROJ 4384
#define CS 64               // SSD chunk size (rechunked; math is exact)
#define NC 32               // LL/CS
#define BLTOT (BB*LL)       // 4096

typedef short v8s __attribute__((ext_vector_type(8)));
typedef float v4f __attribute__((ext_vector_type(4)));

__device__ __forceinline__ float b2f(unsigned short h) {
  union { unsigned int u; float f; } v; v.u = ((unsigned int)h) << 16; return v.f;
}
__device__ __forceinline__ unsigned short f2b(float f) {
  union { float f; unsigned int u; } v; v.f = f;
  unsigned int u = v.u;
  return (unsigned short)((u + 0x7fffu + ((u >> 16) & 1u)) >> 16);
}
__device__ __forceinline__ v4f mfma16(v8s a, v8s b, v4f c) {
  return __builtin_amdgcn_mfma_f32_16x16x32_bf16(a, b, c, 0, 0, 0);
}
// async global->LDS, 16B per lane; LDS dest = wave-uniform base + lane*16
__device__ __forceinline__ void gl_lds16(const unsigned short* g, unsigned short* l) {
  __builtin_amdgcn_global_load_lds(
      (const __attribute__((address_space(1))) void*)(g),
      (__attribute__((address_space(3))) void*)(l), 16, 0, 0);
}

// ---------------- fused fp32 -> bf16 conversion (3 tensors, 1 launch) ----------------
__global__ __launch_bounds__(256) void cvt3_kernel(
    const float* __restrict__ a, unsigned short* __restrict__ oa, int na4,
    const float* __restrict__ b, unsigned short* __restrict__ ob, int nb4,
    const float* __restrict__ c, unsigned short* __restrict__ oc, int nc4)
{
  int i = blockIdx.x * 256 + threadIdx.x;
  const float* src; unsigned short* dst; int j;
  if (i < na4) { src = a; dst = oa; j = i; }
  else if (i < na4 + nb4) { src = b; dst = ob; j = i - na4; }
  else if (i < na4 + nb4 + nc4) { src = c; dst = oc; j = i - na4 - nb4; }
  else return;
  float4 v = ((const float4*)src)[j];
  ushort4 o;
  o.x = f2b(v.x); o.y = f2b(v.y); o.z = f2b(v.z); o.w = f2b(v.w);
  ((ushort4*)dst)[j] = o;
}

// ---------------- bf16 GEMM: 128 x TN tile, 256 threads ----------------
// DBUF=0: exact r0 single-buffer m97 loop — best for gemm1 (TN=128): 32 KB LDS keeps
//   4+ blocks/CU; cross-block wave overlap hides the pre-barrier drain.
// DBUF=1: stage-early double-buffer — best for gemm2 (TN=64): grid-limited 2 blocks/CU,
//   dbuf LDS (48 KB) still allows 3/CU so the pipeline is free (r5 A/B: −3.6 µs).
template<int TN, int OUT_BF16, int DBUF>
__global__ __launch_bounds__(256) void gemm_bt(
    const unsigned short* __restrict__ A, const unsigned short* __restrict__ Bt,
    void* __restrict__ Cout, int M, int N, int K, int ldc)
{
  constexpr int NT = TN / 32;                 // n-tiles per wave
  constexpr int NB = DBUF ? 2 : 1;
  const int bm = blockIdx.x, bn = blockIdx.y;
  const int tid = threadIdx.x;
  const int wave = tid >> 6, lane = tid & 63;
  const int wm = wave & 1, wn = wave >> 1;
  const int q = lane >> 4, lr = lane & 15;

  __shared__ __align__(16) unsigned short As[NB][128 * 64];
  __shared__ __align__(16) unsigned short Bs[NB][TN * 64];

  v4f acc[4][NT];
#pragma unroll
  for (int i = 0; i < 4; i++)
#pragma unroll
    for (int j = 0; j < NT; j++) acc[i][j] = v4f{0.f, 0.f, 0.f, 0.f};

  const int lrow = lane >> 3;                 // 0..7 (row within 8-row group)
  const int gchunk = (lane & 7) ^ lrow;       // swizzled source 16B-chunk

#define STAGE_TILE(bufi, k0) do {                                              \
    _Pragma("unroll")                                                          \
    for (int it = 0; it < 4; ++it) {                                           \
      int r = wave * 32 + it * 8 + lrow;                                       \
      gl_lds16(A + (size_t)(bm * 128 + r) * K + (k0) + gchunk * 8,             \
               &As[bufi][(wave * 32 + it * 8) * 64]);                          \
    }                                                                          \
    _Pragma("unroll")                                                          \
    for (int it = 0; it < TN / 32; ++it) {                                     \
      int rloc = wave * (TN / 4) + it * 8;                                     \
      int rb = bn * TN + rloc + lrow; if (rb >= N) rb = N - 1;                 \
      gl_lds16(Bt + (size_t)rb * K + (k0) + gchunk * 8, &Bs[bufi][rloc * 64]); \
    }                                                                          \
  } while (0)

#define COMPUTE_TILE(bufi) do {                                                \
    const unsigned short* __restrict__ Ab = As[bufi];                          \
    const unsigned short* __restrict__ Bb = Bs[bufi];                          \
    _Pragma("unroll")                                                          \
    for (int ks = 0; ks < 64; ks += 32) {                                      \
      const int c0 = (ks >> 3) + q;                                            \
      v8s af[4], bf[NT];                                                       \
      _Pragma("unroll")                                                        \
      for (int mt = 0; mt < 4; ++mt) {                                         \
        int r = wm * 64 + mt * 16 + lr;                                        \
        af[mt] = *(const v8s*)&Ab[r * 64 + ((c0 ^ (r & 7)) << 3)];             \
      }                                                                        \
      _Pragma("unroll")                                                        \
      for (int nt = 0; nt < NT; ++nt) {                                        \
        int r = wn * (TN / 2) + nt * 16 + lr;                                  \
        bf[nt] = *(const v8s*)&Bb[r * 64 + ((c0 ^ (r & 7)) << 3)];             \
      }                                                                        \
      _Pragma("unroll")                                                        \
      for (int mt = 0; mt < 4; ++mt)                                           \
        _Pragma("unroll")                                                      \
        for (int nt = 0; nt < NT; ++nt)                                        \
          acc[mt][nt] = mfma16(af[mt], bf[nt], acc[mt][nt]);                   \
    }                                                                          \
  } while (0)

#define WAIT_BARRIER() do {                                                    \
    __builtin_amdgcn_sched_barrier(0);                                         \
    asm volatile("s_waitcnt vmcnt(0) lgkmcnt(0)\ns_barrier" ::: "memory");     \
  } while (0)

  if constexpr (DBUF == 0) {
    // r0-exact single-buffer loop
    for (int k0 = 0; k0 < K; k0 += 64) {
      __syncthreads();
      STAGE_TILE(0, k0);
      __syncthreads();
      COMPUTE_TILE(0);
    }
  } else {
    const int nkt = K >> 6;
    STAGE_TILE(0, 0);
    WAIT_BARRIER();
    for (int kt = 0; kt < nkt; ++kt) {
      const int cb = kt & 1;
      if (kt + 1 < nkt) STAGE_TILE(cb ^ 1, (kt + 1) << 6);
      COMPUTE_TILE(cb);
      if (kt + 1 < nkt) WAIT_BARRIER();
    }
  }
#undef STAGE_TILE
#undef COMPUTE_TILE
#undef WAIT_BARRIER

#pragma unroll
  for (int mt = 0; mt < 4; ++mt) {
#pragma unroll
    for (int nt = 0; nt < NT; ++nt) {
      int row = bm * 128 + wm * 64 + mt * 16 + q * 4;
      int col = bn * TN + wn * (TN / 2) + nt * 16 + lr;
      if (col < N) {
#pragma unroll
        for (int r = 0; r < 4; ++r) {
          float v = acc[mt][nt][r];
          if (OUT_BF16) ((unsigned short*)Cout)[(size_t)(row + r) * ldc + col] = f2b(v);
          else          ((float*)Cout)[(size_t)(row + r) * ldc + col] = v;
        }
      }
    }
  }
}

// ---------------- slim tree conv: B/C cols + dt softplus only ----------------
// Emits B both row-major (Bg, for d0_S) and transposed (BgT, for d1's BTw build).
__global__ __launch_bounds__(256) void convBC_kernel(
    const unsigned short* __restrict__ C1, const int* __restrict__ cidx,
    const float* __restrict__ convw, const float* __restrict__ convb,
    const float* __restrict__ dtbias,
    unsigned short* __restrict__ Bg16, unsigned short* __restrict__ Cg16,
    unsigned short* __restrict__ BgT16, float* __restrict__ dtb)
{
  int bl0 = blockIdx.x * 16;           // 16 tokens per block (grid = BLTOT/16 = 256)
  int b = bl0 >> 11;
  int tid = threadIdx.x;
  __shared__ int idxs[64];
  if (tid < 64) {
    int tk = tid >> 2, k = tid & 3;
    idxs[tid] = cidx[b * (4 * LL) + (((bl0 + tk) & 2047) * 4) + k];
  }
  __syncthreads();
  const float4* cw4 = (const float4*)convw;
  int quad = tid & 63;                 // 64 quads cover B/C's 256 cols
  int relc = DSSM + quad * 4;          // xBC-relative col (B/C region)
  float4 w0 = cw4[relc], w1 = cw4[relc + 1], w2 = cw4[relc + 2], w3 = cw4[relc + 3];
  float4 cb = *(const float4*)(convb + relc);
  int tk0 = (tid >> 6) * 4;
  int cc = relc - DSSM;
  unsigned short btc[4][4];            // [col][token] accum for transposed B write
#pragma unroll
  for (int tt = 0; tt < 4; ++tt) {
    int tk = tk0 + tt;
    int bl = bl0 + tk;
    ushort4 rv[4];
#pragma unroll
    for (int k = 0; k < 4; ++k) {
      int iv = idxs[tk * 4 + k];
      rv[k] = (iv > 0) ? *(const ushort4*)(C1 + (size_t)(b * LL + iv - 1) * DPROJ + DSSM + relc)
                       : make_ushort4(0, 0, 0, 0);
    }
    float a0 = cb.x + b2f(rv[0].x) * w0.x + b2f(rv[1].x) * w0.y + b2f(rv[2].x) * w0.z + b2f(rv[3].x) * w0.w;
    float a1 = cb.y + b2f(rv[0].y) * w1.x + b2f(rv[1].y) * w1.y + b2f(rv[2].y) * w1.z + b2f(rv[3].y) * w1.w;
    float a2 = cb.z + b2f(rv[0].z) * w2.x + b2f(rv[1].z) * w2.y + b2f(rv[2].z) * w2.z + b2f(rv[3].z) * w2.w;
    float a3 = cb.w + b2f(rv[0].w) * w3.x + b2f(rv[1].w) * w3.y + b2f(rv[2].w) * w3.z + b2f(rv[3].w) * w3.w;
    ushort4 o;
    o.x = f2b(a0 / (1.f + __expf(-a0)));
    o.y = f2b(a1 / (1.f + __expf(-a1)));
    o.z = f2b(a2 / (1.f + __expf(-a2)));
    o.w = f2b(a3 / (1.f + __expf(-a3)));
    if (cc < DST) {
      *(ushort4*)(Bg16 + (size_t)bl * DST + cc) = o;
      btc[0][tt] = o.x; btc[1][tt] = o.y; btc[2][tt] = o.z; btc[3][tt] = o.w;
    } else {
      *(ushort4*)(Cg16 + (size_t)bl * DST + (cc - DST)) = o;
    }
  }
  if (cc < DST) {
#pragma unroll
    for (int c = 0; c < 4; ++c)
      *(ushort4*)(BgT16 + (size_t)(cc + c) * BLTOT + bl0 + tk0) =
          make_ushort4(btc[c][0], btc[c][1], btc[c][2], btc[c][3]);
  }
  for (int u = tid; u < 16 * NH; u += 256) {   // 16 tokens x 32 heads
    int tk = u >> 5, hh = u & 31;
    int bl = bl0 + tk;
    float raw = b2f(C1[(size_t)bl * DPROJ + DSSM + CONVD + hh]) + dtbias[hh];
    float dtv = (raw > 20.f) ? raw : log1pf(__expf(raw));
    dtb[(size_t)bl * NH + hh] = dtv;
  }
}

// ---------------- S hoist: S[t][s] = sum_n C[t][n]*B[s][n], per (b,chunk) ----------
// S is head-independent (NGROUPS=1) — was computed 32x redundantly inside d1
// (40% of its MFMAs + the B-tile stage). Computed ONCE here, fp32 (1 MB, L2-hot).
// Exact same MFMA fragment mapping as d1's old S loop -> bit-identical values.
__global__ __launch_bounds__(256) void d0_S(
    const unsigned short* __restrict__ Bg16, const unsigned short* __restrict__ Cg16,
    float* __restrict__ Sg)
{
  int gid = blockIdx.x;                 // b*NC + ci  (64 blocks)
  int tid = threadIdx.x, wave = tid >> 6, lane = tid & 63, q = lane >> 4, lr = lane & 15;
  __shared__ __align__(16) unsigned short Bn[CS * 136];
  const size_t blbase = (size_t)(gid >> 5) * LL + (gid & 31) * CS;
#pragma unroll
  for (int g = 0; g < 8; ++g) {
    int f = g * 256 + tid;              // s(64) x n-quads(32)
    int s = f >> 5, c4 = (f & 31) * 4;
    *(ushort4*)&Bn[s * 136 + c4] = *(const ushort4*)(Bg16 + (blbase + s) * DST + c4);
  }
  __syncthreads();
  v4f accS[4];
#pragma unroll
  for (int i = 0; i < 4; i++) accS[i] = v4f{0.f, 0.f, 0.f, 0.f};
#pragma unroll
  for (int ks = 0; ks < 128; ks += 32) {
    v8s a = *(const v8s*)(Cg16 + (blbase + wave * 16 + lr) * DST + ks + q * 8);
#pragma unroll
    for (int si = 0; si < 4; ++si) {
      v8s bb = *(const v8s*)&Bn[(si * 16 + lr) * 136 + ks + q * 8];
      accS[si] = mfma16(a, bb, accS[si]);
    }
  }
  float* So = Sg + (size_t)gid * (CS * CS);
#pragma unroll
  for (int si = 0; si < 4; ++si)
#pragma unroll
    for (int r = 0; r < 4; ++r)
      So[(wave * 16 + q * 4 + r) * CS + si * 16 + lr] = accS[si][r];
}

// ---------------- SSD intra-chunk (slim): x-conv fused + Yd + D*x, states^T --------
// S read from Sg (precomputed once per chunk by d0_S); no B-tile stage, no S-MFMAs.
// LDS 44->38 KB (4 blocks/CU), barriers 3->2. Bit-identical math to the old path.
__global__ __launch_bounds__(256) void d1_intra(
    const unsigned short* __restrict__ C1, const int* __restrict__ cidx,
    const float* __restrict__ convw, const float* __restrict__ convb,
    const unsigned short* __restrict__ BgT16, const float* __restrict__ Sg,
    const float* __restrict__ dtb,
    const float* __restrict__ A_log, const float* __restrict__ Dp,
    unsigned short* __restrict__ y16, unsigned short* __restrict__ statesb,
    float* __restrict__ cdb, float* __restrict__ acumb)
{
  int gid = blockIdx.x;
  int h = gid & 31, ci = (gid >> 5) & 31, b = gid >> 10;
  int tid = threadIdx.x, wave = tid >> 6, lane = tid & 63, q = lane >> 4, lr = lane & 15;

  __shared__ __align__(16) unsigned short G[CS * 72];     // G[t][s] (stride 72)
  __shared__ __align__(16) unsigned short BTw[DST * 72];  // B^T[n][s] * dec[s] * dt[s]
  __shared__ __align__(16) unsigned short xT[HD * 72];    // x^T[p][s]  (no dt)
  __shared__ float dt_s[CS], ac_s[CS], dec_s[CS];
  __shared__ int idxs[CS * 4];          // tree indices for this chunk's 64 tokens
  __shared__ float wls[HD * 4];         // conv weights for this head's 64 x-cols
  __shared__ float bls[HD];             // conv bias

  const size_t blbase = (size_t)b * LL + ci * CS;
  const size_t chbase = (size_t)(b * NC + ci) * NH + h;
  float Ah = -__expf(A_log[h]);

  // wave0: dt load + shuffle inclusive scan (no barriers)
  if (wave == 0) {
    float d = dtb[(blbase + lane) * NH + h];
    float a = d * Ah;
#pragma unroll
    for (int off = 1; off < 64; off <<= 1) {
      float u = __shfl_up(a, off, 64);
      if (lane >= off) a += u;
    }
    float tot = __shfl(a, 63, 64);
    dt_s[lane] = d;
    ac_s[lane] = a;
    dec_s[lane] = __expf(tot - a);
    acumb[chbase * CS + lane] = a;
    if (lane == 0) cdb[chbase] = __expf(tot);
  }
  // stage tree indices + conv weights/bias for this head's x-cols
  {
    int s = tid >> 2, k = tid & 3;      // 256 threads = 64 tokens x 4 taps
    idxs[tid] = cidx[b * (4 * LL) + (ci * CS + s) * 4 + k];
  }
  if (tid < HD) *(float4*)&wls[tid * 4] = *(const float4*)(convw + (h * HD + tid) * 4);
  if (tid < HD / 4) *(float4*)&bls[tid * 4] = *(const float4*)(convb + h * HD + tid * 4);
  __syncthreads();                      // barrier 1 (dt_s/dec_s/ac_s ready)

  // BTw[n][s] = BgT[n][tok] * dec[s] * dt[s]  (reg-staged, conflict-free)
#pragma unroll
  for (int g = 0; g < 8; ++g) {
    int f = g * 256 + tid;              // n(128) x s-quads(16)
    int n = f >> 4, s4 = (f & 15) * 4;
    ushort4 bv = *(const ushort4*)(BgT16 + (size_t)n * BLTOT + blbase + s4);
    ushort4 o;
    o.x = f2b(b2f(bv.x) * dec_s[s4 + 0] * dt_s[s4 + 0]);
    o.y = f2b(b2f(bv.y) * dec_s[s4 + 1] * dt_s[s4 + 1]);
    o.z = f2b(b2f(bv.z) * dec_s[s4 + 2] * dt_s[s4 + 2]);
    o.w = f2b(b2f(bv.w) * dec_s[s4 + 3] * dt_s[s4 + 3]);
    *(ushort4*)&BTw[n * 72 + s4] = o;
  }

  // fused x tree-conv -> xT[p][s]
#pragma unroll
  for (int g = 0; g < 4; ++g) {
    int f = g * 256 + tid;              // s(64) x p-quads(16)
    int s = f >> 4, p4 = (f & 15) * 4;
    ushort4 rv[4];
#pragma unroll
    for (int k = 0; k < 4; ++k) {
      int iv = idxs[s * 4 + k];
      rv[k] = (iv > 0) ? *(const ushort4*)(C1 + (size_t)(b * LL + iv - 1) * DPROJ + DSSM + h * HD + p4)
                       : make_ushort4(0, 0, 0, 0);
    }
    float4 w0 = *(const float4*)&wls[(p4 + 0) * 4];
    float4 w1 = *(const float4*)&wls[(p4 + 1) * 4];
    float4 w2 = *(const float4*)&wls[(p4 + 2) * 4];
    float4 w3 = *(const float4*)&wls[(p4 + 3) * 4];
    float a0 = bls[p4 + 0] + b2f(rv[0].x) * w0.x + b2f(rv[1].x) * w0.y + b2f(rv[2].x) * w0.z + b2f(rv[3].x) * w0.w;
    float a1 = bls[p4 + 1] + b2f(rv[0].y) * w1.x + b2f(rv[1].y) * w1.y + b2f(rv[2].y) * w1.z + b2f(rv[3].y) * w1.w;
    float a2 = bls[p4 + 2] + b2f(rv[0].z) * w2.x + b2f(rv[1].z) * w2.y + b2f(rv[2].z) * w2.z + b2f(rv[3].z) * w2.w;
    float a3 = bls[p4 + 3] + b2f(rv[0].w) * w3.x + b2f(rv[1].w) * w3.y + b2f(rv[2].w) * w3.z + b2f(rv[3].w) * w3.w;
    xT[(p4 + 0) * 72 + s] = f2b(a0 / (1.f + __expf(-a0)));
    xT[(p4 + 1) * 72 + s] = f2b(a1 / (1.f + __expf(-a1)));
    xT[(p4 + 2) * 72 + s] = f2b(a2 / (1.f + __expf(-a2)));
    xT[(p4 + 3) * 72 + s] = f2b(a3 / (1.f + __expf(-a3)));
  }

  // G[t][s] = S[t][s] * exp(Acum[t]-Acum[s]) * dt[s], masked s<=t  (S from Sg, L2-hot)
  {
    const float* Sc = Sg + (size_t)(b * NC + ci) * (CS * CS);
    int tbase = wave * 16 + q * 4;
#pragma unroll
    for (int si = 0; si < 4; ++si) {
      int s = si * 16 + lr;
      float ds = dt_s[s], as = ac_s[s];
#pragma unroll
      for (int r = 0; r < 4; ++r) {
        int tt = tbase + r;
        float g = 0.f;
        if (s <= tt) g = Sc[tt * CS + s] * __expf(ac_s[tt] - as) * ds;
        G[tt * 72 + s] = f2b(g);
      }
    }
  }
  __syncthreads();                      // barrier 2 (G/xT/BTw written)

  // Yd[t][p] = G @ x ; states^T[p][n] = sum_s xT[p][s]*BTw[n][s]
  v4f accY[4], accPT[4][2];
#pragma unroll
  for (int i = 0; i < 4; i++) {
    accY[i] = v4f{0.f,0.f,0.f,0.f};
    accPT[i][0] = v4f{0.f,0.f,0.f,0.f};
    accPT[i][1] = v4f{0.f,0.f,0.f,0.f};
  }
  int nw = wave * 32;                   // wave covers n in [nw, nw+32)
#pragma unroll
  for (int ks = 0; ks < 64; ks += 32) {
    v8s xf[4];
#pragma unroll
    for (int i = 0; i < 4; ++i) xf[i] = *(const v8s*)&xT[(i * 16 + lr) * 72 + ks + q * 8];
    v8s aG  = *(const v8s*)&G[(wave * 16 + lr) * 72 + ks + q * 8];
    v8s bw0 = *(const v8s*)&BTw[(nw + lr) * 72 + ks + q * 8];
    v8s bw1 = *(const v8s*)&BTw[(nw + 16 + lr) * 72 + ks + q * 8];
#pragma unroll
    for (int nt = 0; nt < 4; ++nt) {
      accY[nt] = mfma16(aG, xf[nt], accY[nt]);
      accPT[nt][0] = mfma16(xf[nt], bw0, accPT[nt][0]);
      accPT[nt][1] = mfma16(xf[nt], bw1, accPT[nt][1]);
    }
  }

  // epilogue: y = Yd + D*x  (x from LDS xT)
  float Dh = Dp[h];
#pragma unroll
  for (int nt = 0; nt < 4; ++nt) {
    int p = nt * 16 + lr;
#pragma unroll
    for (int r = 0; r < 4; ++r) {
      int t = wave * 16 + q * 4 + r;
      float xv = b2f(xT[p * 72 + t]);
      y16[(blbase + t) * DSSM + h * HD + p] = f2b(accY[nt][r] + Dh * xv);
    }
  }
  // epilogue: states^T  (layout [p][n], p<HD rows, n<DST cols)
  size_t sbase = chbase * (DST * HD);
#pragma unroll
  for (int mt = 0; mt < 4; ++mt) {
#pragma unroll
    for (int nt = 0; nt < 2; ++nt) {
      int n = nw + nt * 16 + lr;
#pragma unroll
      for (int r = 0; r < 4; ++r) {
        int p = mt * 16 + q * 4 + r;
        statesb[sbase + (size_t)p * DST + n] = f2b(accPT[mt][nt][r]);
      }
    }
  }
}

// ---------------- state passing: vectorized (ushort4) register scan ----------------
// 512 blocks: (b,h) x 8 segments; 4 contiguous elems/thread over 32 chunks.
__global__ __launch_bounds__(256) void d2_scan(
    unsigned short* __restrict__ statesb, const float* __restrict__ cdb)
{
  int g = blockIdx.x;
  int seg = g & 7, bh = g >> 3;
  int b = bh >> 5, h = bh & 31;
  int e4 = seg * 1024 + threadIdx.x * 4;   // 0..8188, 4 elems/thread
  const size_t cstride = (size_t)NH * DST * HD;
  size_t base = ((size_t)(b * NC) * NH + h) * (DST * HD) + e4;
  ushort4 st[NC];
#pragma unroll
  for (int ci = 0; ci < NC; ++ci) st[ci] = *(const ushort4*)(statesb + base + ci * cstride);
  float r0 = 0.f, r1 = 0.f, r2 = 0.f, r3 = 0.f;
#pragma unroll
  for (int ci = 0; ci < NC; ++ci) {
    float cd = cdb[(b * NC + ci) * NH + h];
    *(ushort4*)(statesb + base + ci * cstride) =
        make_ushort4(f2b(r0), f2b(r1), f2b(r2), f2b(r3));   // prev entering chunk ci
    r0 = r0 * cd + b2f(st[ci].x);
    r1 = r1 * cd + b2f(st[ci].y);
    r2 = r2 * cd + b2f(st[ci].z);
    r3 = r3 * cd + b2f(st[ci].w);
  }
}

// ---------------- SSD inter-chunk: Y += exp(Acum[t]) * C @ prev^T ----------------
// prev stored [p][n] -> straight vector staging; D*x already folded into d1
__global__ __launch_bounds__(256) void d3_inter(
    const unsigned short* __restrict__ Cg16,
    const unsigned short* __restrict__ statesb, const float* __restrict__ acumb,
    unsigned short* __restrict__ y16)
{
  int gid = blockIdx.x;
  int h = gid & 31, ci = (gid >> 5) & 31, b = gid >> 10;
  int tid = threadIdx.x, wave = tid >> 6, lane = tid & 63, q = lane >> 4, lr = lane & 15;
  __shared__ __align__(16) unsigned short pT[HD * 136];   // prev^T[p][n]
  __shared__ __align__(16) float ys[CS * 68];             // y-stage (fp32)
  __shared__ float ea[CS];
  const size_t blbase = (size_t)b * LL + ci * CS;
  const size_t chbase = (size_t)(b * NC + ci) * NH + h;
  if (tid < CS) ea[tid] = __expf(acumb[chbase * CS + tid]);
  size_t sbase = chbase * (DST * HD);
  // stage prev^T: plain vector copy (64 rows x 128 cols)
#pragma unroll
  for (int g = 0; g < 8; ++g) {
    int f = g * 256 + tid;              // p(64) x n-quads(32)
    int p = f >> 5, c4 = (f & 31) * 4;
    *(ushort4*)&pT[p * 136 + c4] = *(const ushort4*)(statesb + sbase + (size_t)p * DST + c4);
  }
  __syncthreads();
  v4f acc[4];
#pragma unroll
  for (int i = 0; i < 4; i++) acc[i] = v4f{0.f, 0.f, 0.f, 0.f};
#pragma unroll
  for (int ks = 0; ks < 128; ks += 32) {
    v8s a = *(const v8s*)(Cg16 + (blbase + wave * 16 + lr) * DST + ks + q * 8);
#pragma unroll
    for (int nt = 0; nt < 4; ++nt) {
      v8s bb = *(const v8s*)&pT[(nt * 16 + lr) * 136 + ks + q * 8];
      acc[nt] = mfma16(a, bb, acc[nt]);
    }
  }
  // stage Yoff to LDS (fp32), then vectorized RMW epilogue
#pragma unroll
  for (int nt = 0; nt < 4; ++nt) {
#pragma unroll
    for (int r = 0; r < 4; ++r)
      ys[(wave * 16 + q * 4 + r) * 68 + nt * 16 + lr] = acc[nt][r];
  }
  __syncthreads();
#pragma unroll
  for (int it = 0; it < 2; ++it) {
    int unit = it * 256 + tid;          // t(64) x p8(8)
    int t = unit >> 3, p8 = (unit & 7) * 8;
    float ea_t = ea[t];
    size_t off = (blbase + t) * DSSM + h * HD + p8;
    uint4 yv = *(const uint4*)(y16 + off);
    float4 o0 = *(const float4*)&ys[t * 68 + p8];
    float4 o1 = *(const float4*)&ys[t * 68 + p8 + 4];
    const unsigned int* yu = (const unsigned int*)&yv;
    float oo[8] = {o0.x, o0.y, o0.z, o0.w, o1.x, o1.y, o1.z, o1.w};
    unsigned int ro[4];
#pragma unroll
    for (int d = 0; d < 4; ++d) {
      unsigned short y0 = (unsigned short)(yu[d] & 0xffffu), y1 = (unsigned short)(yu[d] >> 16);
      float v0 = b2f(y0) + ea_t * oo[d * 2 + 0];
      float v1 = b2f(y1) + ea_t * oo[d * 2 + 1];
      ro[d] = (unsigned int)f2b(v0) | ((unsigned int)f2b(v1) << 16);
    }
    *(uint4*)(y16 + off) = make_uint4(ro[0], ro[1], ro[2], ro[3]);
  }
}

// ---------------- gated RMSNorm (vectorized) ----------------
__global__ __launch_bounds__(256) void norm_kernel(
    const unsigned short* __restrict__ y16, const unsigned short* __restrict__ C1,
    const float* __restrict__ normw, unsigned short* __restrict__ yzn)
{
  int bl = blockIdx.x;
  int tid = threadIdx.x;
  int wave = tid >> 6, lane = tid & 63;
  int c8 = tid * 8;
  uint4 yv = *(const uint4*)(y16 + (size_t)bl * DSSM + c8);
  uint4 zv = *(const uint4*)(C1 + (size_t)bl * DPROJ + c8);   // z = first 2048 cols
  const unsigned int* yu = (const unsigned int*)&yv;
  const unsigned int* zu = (const unsigned int*)&zv;
  float vals[8];
  float ss = 0.f;
#pragma unroll
  for (int d = 0; d < 4; ++d) {
    unsigned short y0 = (unsigned short)(yu[d] & 0xffffu), y1 = (unsigned short)(yu[d] >> 16);
    unsigned short z0 = (unsigned short)(zu[d] & 0xffffu), z1 = (unsigned short)(zu[d] >> 16);
    float zf0 = b2f(z0), zf1 = b2f(z1);
    float v0 = b2f(y0) * (zf0 / (1.f + __expf(-zf0)));
    float v1 = b2f(y1) * (zf1 / (1.f + __expf(-zf1)));
    vals[d * 2] = v0; vals[d * 2 + 1] = v1;
    ss += v0 * v0 + v1 * v1;
  }
#pragma unroll
  for (int off = 32; off > 0; off >>= 1) ss += __shfl_down(ss, off);
  __shared__ float red[4];
  if (lane == 0) red[wave] = ss;
  __syncthreads();
  float tot = red[0] + red[1] + red[2] + red[3];
  float scale = rsqrtf(tot * (1.f / 2048.f) + 1e-5f);
  float4 w0 = *(const float4*)(normw + c8);
  float4 w1 = *(const float4*)(normw + c8 + 4);
  float ws[8] = {w0.x, w0.y, w0.z, w0.w, w1.x, w1.y, w1.z, w1.w};
  unsigned int ro[4];
#pragma unroll
  for (int d = 0; d < 4; ++d) {
    unsigned short r0 = f2b(vals[d * 2] * scale * ws[d * 2]);
    unsigned short r1 = f2b(vals[d * 2 + 1] * scale * ws[d * 2 + 1]);
    ro[d] = (unsigned int)r0 | ((unsigned int)r1 << 16);
  }
  *(uint4*)(yzn + (size_t)bl * DSSM + c8) = make_uint4(ro[0], ro[1], ro[2], ro[3]);
}

// ---------------- host launch ----------------
extern "C" void kernel_launch(void* const* d_in, const int* in_sizes, int n_in,
                              void* d_out, int out_size, void* d_ws, size_t ws_size,
                              hipStream_t stream) {
  const float* u      = (const float*)d_in[0];
  const int*   cidx   = (const int*)d_in[1];
  const float* W_in   = (const float*)d_in[2];
  const float* convw  = (const float*)d_in[3];
  const float* convb  = (const float*)d_in[4];
  const float* dtbias = (const float*)d_in[5];
  const float* A_log  = (const float*)d_in[6];
  const float* Dp     = (const float*)d_in[7];
  const float* normw  = (const float*)d_in[8];
  const float* W_out  = (const float*)d_in[9];

  char* w = (char*)d_ws;
  size_t off = 0;
  auto alloc = [&](size_t bytes) { char* p = w + off; off += (bytes + 255) & ~(size_t)255; return p; };
  unsigned short* u16     = (unsigned short*)alloc((size_t)BLTOT * DMODEL * 2);
  unsigned short* Win16   = (unsigned short*)alloc((size_t)DPROJ * DMODEL * 2);
  unsigned short* Wout16  = (unsigned short*)alloc((size_t)DMODEL * DSSM * 2);
  unsigned short* C1      = (unsigned short*)alloc((size_t)BLTOT * DPROJ * 2);
  unsigned short* Bg16    = (unsigned short*)alloc((size_t)BLTOT * DST * 2);
  unsigned short* Cg16    = (unsigned short*)alloc((size_t)BLTOT * DST * 2);
  unsigned short* BgT16   = (unsigned short*)alloc((size_t)DST * BLTOT * 2);
  float*          Sg      = (float*)alloc((size_t)BB * NC * CS * CS * 4);
  float*          dtb     = (float*)alloc((size_t)BLTOT * NH * 4);
  float*          acumb   = (float*)alloc((size_t)BB * NC * NH * CS * 4);
  unsigned short* y16     = (unsigned short*)alloc((size_t)BLTOT * DSSM * 2);
  unsigned short* statesb = (unsigned short*)alloc((size_t)BB * NC * NH * DST * HD * 2);
  float*          cdb     = (float*)alloc((size_t)BB * NC * NH * 4);
  unsigned short* yzn     = (unsigned short*)alloc((size_t)BLTOT * DSSM * 2);

  const int na4 = BLTOT * DMODEL / 4, nb4 = DPROJ * DMODEL / 4, nc4 = DMODEL * DSSM / 4;
  cvt3_kernel<<<(na4 + nb4 + nc4 + 255) / 256, 256, 0, stream>>>(
      u, u16, na4, W_in, Win16, nb4, W_out, Wout16, nc4);

  // zxbcdt = u @ W_in^T (bf16 out) — single-buffer m97 (best measured 54.5 µs)
  gemm_bt<128, 1, 0><<<dim3(BLTOT / 128, (DPROJ + 127) / 128), 256, 0, stream>>>(
      u16, Win16, C1, BLTOT, DPROJ, DMODEL, DPROJ);
  convBC_kernel<<<BLTOT / 16, 256, 0, stream>>>(C1, cidx, convw, convb, dtbias,
                                                Bg16, Cg16, BgT16, dtb);
  d0_S<<<BB * NC, 256, 0, stream>>>(Bg16, Cg16, Sg);
  d1_intra<<<BB * NC * NH, 256, 0, stream>>>(C1, cidx, convw, convb, BgT16, Sg,
                                             dtb, A_log, Dp, y16, statesb, cdb, acumb);
  d2_scan<<<BB * NH * 8, 256, 0, stream>>>(statesb, cdb);
  d3_inter<<<BB * NC * NH, 256, 0, stream>>>(Cg16, statesb, acumb, y16);
  norm_kernel<<<BLTOT, 256, 0, stream>>>(y16, C1, normw, yzn);
  // out = yzn @ W_out^T (fp32 out) — double-buffered (grid-limited; r5 A/B: −3.6 µs)
  gemm_bt<64, 0, 1><<<dim3(BLTOT / 128, DMODEL / 64), 256, 0, stream>>>(
      yzn, Wout16, (float*)d_out, BLTOT, DMODEL, DSSM, DMODEL);
}